// Round 12
// baseline (744.982 us; speedup 1.0000x reference)
//
#include <hip/hip_runtime.h>
#include <hip/hip_bf16.h>
#include <cmath>
#include <cstdint>

typedef _Float16 f16;
typedef _Float16 f16x8 __attribute__((ext_vector_type(8)));
typedef float f32x4 __attribute__((ext_vector_type(4)));

#define D_ 1024
#define S_ 2048

// Split-fp16 fp32 emulation: tensor T stored as (hi, lo) f16 pair of T*1024;
// GEMM = 3 MFMA passes (hh, hl, lh).  3-pass REQUIRED wherever the result
// feeds (transitively) the rl>0 branch boundary; final O mu-GEMM -> 2-pass.
//
// Config = round-7 best-total (v4 duals 512-thr reg-pipelined + 4-wave attn),
// plus: V-dual epilogue writes V TRANSPOSED directly (EPI=2), removing the
// separate transpose_v dispatch (64MB r + 64MB w saved).

__device__ __forceinline__ void gload_lds16(const void* g, void* l) {
  __builtin_amdgcn_global_load_lds(
      (const __attribute__((address_space(1))) void*)(unsigned long long)(uintptr_t)g,
      (__attribute__((address_space(3))) void*)(unsigned int)(uintptr_t)l,
      16, 0, 0);
}

__device__ __forceinline__ int lds_off(int row, int cb) {
  return (row << 5) + ((cb ^ ((row >> 1) & 3)) << 3);
}

__device__ __forceinline__ void split1024(float v, f16& h, f16& l) {
  float s = v * 1024.f;  // exact
  h = (f16)s;
  l = (f16)(s - (float)h);
}

#define MFMA16(a, b, c) __builtin_amdgcn_mfma_f32_16x16x32_f16((a), (b), (c), 0, 0, 0)

// 4-wave stage helper for the attention kernels.
__device__ __forceinline__ void stage_tile(const f16* __restrict__ src, int ld,
                                           f16* lds, int wid, int lane) {
  const int r = (wid << 5) + (lane >> 2);
  const int c = (lane & 3) ^ ((r >> 1) & 3);
  const f16* g0 = src + (size_t)r * ld + (c << 3);
  gload_lds16(g0, lds + (wid << 10));
  gload_lds16(g0 + (size_t)(ld << 4), lds + (wid << 10) + 512);
}

// ------------------------------------------------------------ weights ------
__global__ __launch_bounds__(256) void convert_w(
    const float* __restrict__ s0, const float* __restrict__ s1,
    const float* __restrict__ s2, const float* __restrict__ s3,
    const float* __restrict__ s4, const float* __restrict__ s5,
    const float* __restrict__ s6, const float* __restrict__ s7,
    f16* __restrict__ dst) {
  const float* srcs[8] = {s0, s1, s2, s3, s4, s5, s6, s7};
  const float* sp = srcs[blockIdx.y];
  f16* hi = dst + (size_t)blockIdx.y * 2097152;
  f16* lo = hi + 1048576;
  const int i = (blockIdx.x * 256 + threadIdx.x) << 2;
  float4 f = *(const float4*)(sp + i);
  __align__(8) f16 h4[4], l4[4];
  split1024(f.x, h4[0], l4[0]); split1024(f.y, h4[1], l4[1]);
  split1024(f.z, h4[2], l4[2]); split1024(f.w, h4[3], l4[3]);
  *(uint2*)(hi + i) = *(uint2*)h4;
  *(uint2*)(lo + i) = *(uint2*)l4;
}

__global__ __launch_bounds__(256) void cost_k(
    const float* __restrict__ g0, const float* __restrict__ g1,
    const float* __restrict__ g2, const float* __restrict__ g3,
    float* __restrict__ cost) {
  const float* gp = blockIdx.x == 0 ? g0 : blockIdx.x == 1 ? g1
                   : blockIdx.x == 2 ? g2 : g3;
  const int t = threadIdx.x;
  float4 v = *(const float4*)(gp + (t << 2));
  float mx = fmaxf(fmaxf(fabsf(v.x), fabsf(v.y)), fmaxf(fabsf(v.z), fabsf(v.w)));
  for (int o = 32; o; o >>= 1) mx = fmaxf(mx, __shfl_xor(mx, o, 64));
  __shared__ float red[4];
  if ((t & 63) == 0) red[t >> 6] = mx;
  __syncthreads();
  mx = fmaxf(fmaxf(red[0], red[1]), fmaxf(red[2], red[3]));
  const float den = mx + 1e-9f;
  float4 o = {v.x / den, v.y / den, v.z / den, v.w / den};
  *(float4*)(cost + (blockIdx.x << 10) + (t << 2)) = o;
}

// ----------------------------------------------------------- layernorm -----
__global__ __launch_bounds__(256) void layernorm_k(
    const float* __restrict__ x, const float* __restrict__ g,
    const float* __restrict__ bta, f16* __restrict__ Lh, f16* __restrict__ Ll) {
  const int row = blockIdx.x, t = threadIdx.x;
  const float* xr = x + (size_t)row * D_;
  float4 v = *(const float4*)(xr + (t << 2));
  float s = v.x + v.y + v.z + v.w;
  float q = v.x * v.x + v.y * v.y + v.z * v.z + v.w * v.w;
  for (int o = 32; o; o >>= 1) { s += __shfl_xor(s, o, 64); q += __shfl_xor(q, o, 64); }
  __shared__ float red[8];
  const int wid = t >> 6;
  if ((t & 63) == 0) { red[wid] = s; red[4 + wid] = q; }
  __syncthreads();
  s = red[0] + red[1] + red[2] + red[3];
  q = red[4] + red[5] + red[6] + red[7];
  const float mean = s * (1.f / D_);
  const float var = q * (1.f / D_) - mean * mean;
  const float inv = 1.f / sqrtf(var + 1e-5f);
  float4 gv = *(const float4*)(g + (t << 2));
  float4 bv = *(const float4*)(bta + (t << 2));
  __align__(8) f16 h4[4], l4[4];
  split1024((v.x - mean) * inv * gv.x + bv.x, h4[0], l4[0]);
  split1024((v.y - mean) * inv * gv.y + bv.y, h4[1], l4[1]);
  split1024((v.z - mean) * inv * gv.z + bv.z, h4[2], l4[2]);
  split1024((v.w - mean) * inv * gv.w + bv.w, h4[3], l4[3]);
  const size_t off = (size_t)row * D_ + (t << 2);
  *(uint2*)(Lh + off) = *(uint2*)h4;
  *(uint2*)(Ll + off) = *(uint2*)l4;
}

// --------- dual GEMM + SPL + branch, reg-pipelined phases (v4) -------------
// EPI 0: (hi,lo) pair row-major.  EPI 1: fp32 x+out.  EPI 2: pair TRANSPOSED
// per batch -> VT[b][d][s] (fuses the old transpose_v).
#define MFMA_PHASE(N, BPH, BPL, BMH, BML)                                  \
  __builtin_amdgcn_sched_barrier(0);                                       \
  __builtin_amdgcn_s_setprio(1);                                           \
  _Pragma("unroll") for (int m = 0; m < 4; ++m)                            \
      accP[m][N] = MFMA16(ah[m], (BPH), accP[m][N]);                       \
  _Pragma("unroll") for (int m = 0; m < 4; ++m)                            \
      accP[m][N] = MFMA16(ah[m], (BPL), accP[m][N]);                       \
  _Pragma("unroll") for (int m = 0; m < 4; ++m)                            \
      accP[m][N] = MFMA16(al[m], (BPH), accP[m][N]);                       \
  _Pragma("unroll") for (int m = 0; m < 4; ++m)                            \
      accM[m][N] = MFMA16(ah[m], (BMH), accM[m][N]);                       \
  _Pragma("unroll") for (int m = 0; m < 4; ++m)                            \
      accM[m][N] = MFMA16(ah[m], (BML), accM[m][N]);                       \
  if (MUP == 3) {                                                          \
    _Pragma("unroll") for (int m = 0; m < 4; ++m)                          \
        accM[m][N] = MFMA16(al[m], (BMH), accM[m][N]);                     \
  }                                                                        \
  __builtin_amdgcn_s_setprio(0);

template <int EPI, int MUP>
__global__ __launch_bounds__(512, 1) void dual_gemm_v4(
    const f16* __restrict__ Ah, const f16* __restrict__ Al,
    const f16* __restrict__ Wph, const f16* __restrict__ Wpl,
    const f16* __restrict__ Wmh, const f16* __restrict__ Wml,
    const float* __restrict__ bias, const float* __restrict__ cost,
    const f16* __restrict__ passh, const f16* __restrict__ passl,
    const float* __restrict__ xres, f16* __restrict__ outh,
    f16* __restrict__ outl, float* __restrict__ outf) {
  __shared__ __align__(16) f16 smem[65536];
  const int tid = threadIdx.x, wid = tid >> 6, lane = tid & 63;
  const int row0 = blockIdx.x << 8, col0 = blockIdx.y << 7;
  const int wr = (wid >> 1) << 6, wc = (wid & 1) << 6;
  const int arow = lane & 15, cbk = lane >> 4;

  const int sr = tid >> 2;
  const int sc = ((tid & 3) ^ ((sr >> 1) & 3)) << 3;
  const int wbase = wid << 9;

  const f16* pA0 = Ah + (size_t)(row0 + sr) * D_ + sc;
  const f16* pA1 = Ah + (size_t)(row0 + 128 + sr) * D_ + sc;
  const f16* pL0 = Al + (size_t)(row0 + sr) * D_ + sc;
  const f16* pL1 = Al + (size_t)(row0 + 128 + sr) * D_ + sc;
  const f16* pPh = Wph + (size_t)(col0 + sr) * D_ + sc;
  const f16* pPl = Wpl + (size_t)(col0 + sr) * D_ + sc;
  const f16* pMh = Wmh + (size_t)(col0 + sr) * D_ + sc;
  const f16* pMl = Wml + (size_t)(col0 + sr) * D_ + sc;

  const f32x4 zero = {0.f, 0.f, 0.f, 0.f};
  f32x4 accP[4][4], accM[4][4];
#pragma unroll
  for (int m = 0; m < 4; ++m)
#pragma unroll
    for (int n = 0; n < 4; ++n) { accP[m][n] = zero; accM[m][n] = zero; }

  int aoff[4], boff[4];
#pragma unroll
  for (int m = 0; m < 4; ++m) aoff[m] = lds_off(wr + m * 16 + arow, cbk);
#pragma unroll
  for (int n = 0; n < 4; ++n) boff[n] = lds_off(wc + n * 16 + arow, cbk);

  {
    f16* b = smem;
    gload_lds16(pA0, b + wbase);          gload_lds16(pA1, b + 4096 + wbase);
    gload_lds16(pL0, b + 8192 + wbase);   gload_lds16(pL1, b + 12288 + wbase);
    gload_lds16(pPh, b + 16384 + wbase);  gload_lds16(pPl, b + 20480 + wbase);
    gload_lds16(pMh, b + 24576 + wbase);  gload_lds16(pMl, b + 28672 + wbase);
  }
  asm volatile("s_waitcnt vmcnt(0)" ::: "memory");
  __builtin_amdgcn_s_barrier();
  __builtin_amdgcn_sched_barrier(0);

  int cur = 0;
  for (int t = 0; t < 32; ++t) {
    const f16* bb = smem + (cur << 15);
    f16* nb = smem + ((cur ^ 1) << 15);
    const int kn = (t < 31) ? ((t + 1) << 5) : 0;

    f16x8 ah[4], al[4];
#pragma unroll
    for (int m = 0; m < 4; ++m) {
      ah[m] = *(const f16x8*)&bb[aoff[m]];
      al[m] = *(const f16x8*)&bb[8192 + aoff[m]];
    }
    f16x8 xph = *(const f16x8*)&bb[16384 + boff[0]];
    f16x8 xpl = *(const f16x8*)&bb[20480 + boff[0]];
    f16x8 xmh = *(const f16x8*)&bb[24576 + boff[0]];
    f16x8 xml = *(const f16x8*)&bb[28672 + boff[0]];
    f16x8 yph = *(const f16x8*)&bb[16384 + boff[1]];
    f16x8 ypl = *(const f16x8*)&bb[20480 + boff[1]];
    f16x8 ymh = *(const f16x8*)&bb[24576 + boff[1]];
    f16x8 yml = *(const f16x8*)&bb[28672 + boff[1]];
    gload_lds16(pA0 + kn, nb + wbase);
    gload_lds16(pA1 + kn, nb + 4096 + wbase);
    MFMA_PHASE(0, xph, xpl, xmh, xml)

    xph = *(const f16x8*)&bb[16384 + boff[2]];
    xpl = *(const f16x8*)&bb[20480 + boff[2]];
    xmh = *(const f16x8*)&bb[24576 + boff[2]];
    xml = *(const f16x8*)&bb[28672 + boff[2]];
    gload_lds16(pL0 + kn, nb + 8192 + wbase);
    gload_lds16(pL1 + kn, nb + 12288 + wbase);
    MFMA_PHASE(1, yph, ypl, ymh, yml)

    yph = *(const f16x8*)&bb[16384 + boff[3]];
    ypl = *(const f16x8*)&bb[20480 + boff[3]];
    ymh = *(const f16x8*)&bb[24576 + boff[3]];
    yml = *(const f16x8*)&bb[28672 + boff[3]];
    gload_lds16(pPh + kn, nb + 16384 + wbase);
    gload_lds16(pPl + kn, nb + 20480 + wbase);
    MFMA_PHASE(2, xph, xpl, xmh, xml)

    gload_lds16(pMh + kn, nb + 24576 + wbase);
    gload_lds16(pMl + kn, nb + 28672 + wbase);
    MFMA_PHASE(3, yph, ypl, ymh, yml)

    asm volatile("s_waitcnt vmcnt(0)" ::: "memory");
    __builtin_amdgcn_s_barrier();
    __builtin_amdgcn_sched_barrier(0);
    cur ^= 1;
  }

  // acc = 2^20 * true.  match = acc*2^-25 (incl /32); pre = acc*2^-20.
#pragma unroll
  for (int m = 0; m < 4; ++m) {
    const int rb = row0 + wr + m * 16 + ((lane >> 4) << 2);
#pragma unroll
    for (int n = 0; n < 4; ++n) {
      const int col = col0 + wc + n * 16 + (lane & 15);
      const float cb2 = cost[col], bbv = bias[col];
      __align__(8) f16 th[4], tl[4];
#pragma unroll
      for (int j = 0; j < 4; ++j) {
        const size_t off = (size_t)(rb + j) * D_ + col;
        const float match = accP[m][n][j] * (1.f / 33554432.f);
        const float pre = accM[m][n][j] * (1.f / 1048576.f) + bbv;
        const float comp = pre / (1.f + expf(-pre));
        const float rl = match - cb2;
        float ov;
        if (rl > 0.f) ov = comp * rl;
        else ov = ((float)passh[off] + (float)passl[off]) * (1.f / 1024.f);
        if (EPI == 1) {
          outf[off] = xres[off] + ov;
        } else {
          f16 h, l; split1024(ov, h, l);
          if (EPI == 0) { outh[off] = h; outl[off] = l; }
          else { th[j] = h; tl[j] = l; }
        }
      }
      if (EPI == 2) {
        // transposed write: VT[b][d=col][s], s = row & 2047, b = row >> 11.
        // 256-row tiles never straddle batches; j = 4 consecutive s -> 8B.
        const int bI = rb >> 11, s0r = rb & 2047;
        const size_t toff = ((size_t)bI * D_ + col) * S_ + s0r;
        *(uint2*)(outh + toff) = *(uint2*)th;
        *(uint2*)(outl + toff) = *(uint2*)tl;
      }
    }
  }
}

// ------------------------------------------------- scores = q k^T / 32 -----
__global__ __launch_bounds__(256, 2) void scores_gemm(
    const f16* __restrict__ Qh, const f16* __restrict__ Ql,
    const f16* __restrict__ Kh, const f16* __restrict__ Kl,
    float* __restrict__ SC) {
  const int rt = blockIdx.x, ct = blockIdx.y, b = blockIdx.z;
  if (ct > rt) return;
  __shared__ __align__(16) f16 lQh[4096], lQl[4096], lKh[4096], lKl[4096];
  const int tid = threadIdx.x, wid = tid >> 6, lane = tid & 63;
  const int row0 = rt << 7, col0 = ct << 7;
  const int wr = (wid >> 1) << 6, wc = (wid & 1) << 6;
  const int arow = lane & 15, cb = lane >> 4;
  const f32x4 zero = {0.f, 0.f, 0.f, 0.f};
  f32x4 acc[4][4];
#pragma unroll
  for (int m = 0; m < 4; ++m)
#pragma unroll
    for (int n = 0; n < 4; ++n) acc[m][n] = zero;
  const f16* Qhb = Qh + ((size_t)b * S_ + row0) * D_;
  const f16* Qlb = Ql + ((size_t)b * S_ + row0) * D_;
  const f16* Khb = Kh + ((size_t)b * S_ + col0) * D_;
  const f16* Klb = Kl + ((size_t)b * S_ + col0) * D_;
  for (int k = 0; k < D_; k += 32) {
    stage_tile(Qhb + k, D_, lQh, wid, lane);
    stage_tile(Qlb + k, D_, lQl, wid, lane);
    stage_tile(Khb + k, D_, lKh, wid, lane);
    stage_tile(Klb + k, D_, lKl, wid, lane);
    __syncthreads();
    f16x8 bh[4], bl[4];
#pragma unroll
    for (int n = 0; n < 4; ++n) {
      const int bo = lds_off(wc + n * 16 + arow, cb);
      bh[n] = *(const f16x8*)&lKh[bo];
      bl[n] = *(const f16x8*)&lKl[bo];
    }
#pragma unroll
    for (int m = 0; m < 4; ++m) {
      const int ao = lds_off(wr + m * 16 + arow, cb);
      f16x8 ah = *(const f16x8*)&lQh[ao];
      f16x8 al = *(const f16x8*)&lQl[ao];
#pragma unroll
      for (int n = 0; n < 4; ++n) {
        acc[m][n] = MFMA16(ah, bh[n], acc[m][n]);
        acc[m][n] = MFMA16(ah, bl[n], acc[m][n]);
        acc[m][n] = MFMA16(al, bh[n], acc[m][n]);
      }
    }
    __syncthreads();
  }
  float* scb = SC + (size_t)b * S_ * S_;
#pragma unroll
  for (int m = 0; m < 4; ++m) {
    const int rb = row0 + wr + m * 16 + ((lane >> 4) << 2);
#pragma unroll
    for (int n = 0; n < 4; ++n) {
      const int col = col0 + wc + n * 16 + (lane & 15);
#pragma unroll
      for (int j = 0; j < 4; ++j)
        scb[(size_t)(rb + j) * S_ + col] = acc[m][n][j] * (1.f / 33554432.f);
    }
  }
}

// --------------------------- softmax (causal) + in-place hi/lo f16 pack ----
__global__ __launch_bounds__(256) void softmax_rows(float* __restrict__ SC) {
  const int r = blockIdx.x;
  const int s = r & 2047;
  float* rowf = SC + (size_t)r * S_;
  const int t = threadIdx.x, c0 = t << 3;
  float f[8];
  float4 u0 = *(const float4*)(rowf + c0);
  float4 u1 = *(const float4*)(rowf + c0 + 4);
  f[0] = u0.x; f[1] = u0.y; f[2] = u0.z; f[3] = u0.w;
  f[4] = u1.x; f[5] = u1.y; f[6] = u1.z; f[7] = u1.w;
  float mx = -3.0e38f;
#pragma unroll
  for (int j = 0; j < 8; ++j)
    if (c0 + j <= s) mx = fmaxf(mx, f[j]);
  for (int o = 32; o; o >>= 1) mx = fmaxf(mx, __shfl_xor(mx, o, 64));
  __shared__ float red[8];
  const int wid = t >> 6;
  if ((t & 63) == 0) red[wid] = mx;
  __syncthreads();
  mx = fmaxf(fmaxf(red[0], red[1]), fmaxf(red[2], red[3]));
  float e[8];
  float sum = 0.f;
#pragma unroll
  for (int j = 0; j < 8; ++j) {
    e[j] = (c0 + j <= s) ? expf(f[j] - mx) : 0.f;
    sum += e[j];
  }
  for (int o = 32; o; o >>= 1) sum += __shfl_xor(sum, o, 64);
  if ((t & 63) == 0) red[4 + wid] = sum;
  __syncthreads();
  sum = red[4] + red[5] + red[6] + red[7];
  f16* rowh = (f16*)rowf;
  __align__(16) f16 ph[8], pl[8];
#pragma unroll
  for (int j = 0; j < 8; ++j) {
    float p = (e[j] / sum) * 2048.f;
    ph[j] = (f16)p;
    pl[j] = (f16)(p - (float)ph[j]);
  }
  *(uint4*)(rowh + c0) = *(uint4*)ph;
  *(uint4*)(rowh + 2048 + c0) = *(uint4*)pl;
}

// --------------------------------------------------------- attn = P V ------
__global__ __launch_bounds__(256, 2) void pv_gemm(
    const f16* __restrict__ P, const f16* __restrict__ VTh,
    const f16* __restrict__ VTl, f16* __restrict__ Ath, f16* __restrict__ Atl) {
  const int rt = blockIdx.x, ct = blockIdx.y, b = blockIdx.z;
  __shared__ __align__(16) f16 lPh[4096], lPl[4096], lVh[4096], lVl[4096];
  const int tid = threadIdx.x, wid = tid >> 6, lane = tid & 63;
  const int row0 = rt << 7, col0 = ct << 7;
  const int wr = (wid >> 1) << 6, wc = (wid & 1) << 6;
  const int arow = lane & 15, cb = lane >> 4;
  const f32x4 zero = {0.f, 0.f, 0.f, 0.f};
  f32x4 acc[4][4];
#pragma unroll
  for (int m = 0; m < 4; ++m)
#pragma unroll
    for (int n = 0; n < 4; ++n) acc[m][n] = zero;
  const f16* Pb = P + ((size_t)b * S_ + row0) * 4096;
  const f16* Vhb = VTh + (size_t)b * D_ * S_ + (size_t)col0 * S_;
  const f16* Vlb = VTl + (size_t)b * D_ * S_ + (size_t)col0 * S_;
  const int kend = (rt + 1) << 7;
  for (int k = 0; k < kend; k += 32) {
    stage_tile(Pb + k, 4096, lPh, wid, lane);
    stage_tile(Pb + 2048 + k, 4096, lPl, wid, lane);
    stage_tile(Vhb + k, S_, lVh, wid, lane);
    stage_tile(Vlb + k, S_, lVl, wid, lane);
    __syncthreads();
    f16x8 bh[4], bl[4];
#pragma unroll
    for (int n = 0; n < 4; ++n) {
      const int bo = lds_off(wc + n * 16 + arow, cb);
      bh[n] = *(const f16x8*)&lVh[bo];
      bl[n] = *(const f16x8*)&lVl[bo];
    }
#pragma unroll
    for (int m = 0; m < 4; ++m) {
      const int ao = lds_off(wr + m * 16 + arow, cb);
      f16x8 ah = *(const f16x8*)&lPh[ao];
      f16x8 al = *(const f16x8*)&lPl[ao];
#pragma unroll
      for (int n = 0; n < 4; ++n) {
        acc[m][n] = MFMA16(ah, bh[n], acc[m][n]);
        acc[m][n] = MFMA16(ah, bl[n], acc[m][n]);
        acc[m][n] = MFMA16(al, bh[n], acc[m][n]);
      }
    }
    __syncthreads();
  }
  // acc = 2048*1024 * attn  -> attn = acc * 2^-21
#pragma unroll
  for (int m = 0; m < 4; ++m) {
    const int rb = row0 + wr + m * 16 + ((lane >> 4) << 2);
#pragma unroll
    for (int n = 0; n < 4; ++n) {
      const int col = col0 + wc + n * 16 + (lane & 15);
#pragma unroll
      for (int j = 0; j < 4; ++j) {
        const float at = acc[m][n][j] * (1.f / 2097152.f);
        const size_t off = ((size_t)b * S_ + rb + j) * D_ + col;
        f16 h, l; split1024(at, h, l);
        Ath[off] = h; Atl[off] = l;
      }
    }
  }
}

// ---------------------------------------------------------------- host -----
extern "C" void kernel_launch(void* const* d_in, const int* in_sizes, int n_in,
                              void* d_out, int out_size, void* d_ws, size_t ws_size,
                              hipStream_t stream) {
  (void)in_sizes; (void)n_in; (void)out_size; (void)ws_size;
  const float* x      = (const float*)d_in[0];
  const float* ln_g   = (const float*)d_in[1];
  const float* ln_b   = (const float*)d_in[2];
  const float* q_mu_w = (const float*)d_in[3];
  const float* q_mu_b = (const float*)d_in[4];
  const float* q_pro  = (const float*)d_in[5];
  const float* q_gate = (const float*)d_in[6];
  const float* k_mu_w = (const float*)d_in[7];
  const float* k_mu_b = (const float*)d_in[8];
  const float* k_pro  = (const float*)d_in[9];
  const float* k_gate = (const float*)d_in[10];
  const float* v_mu_w = (const float*)d_in[11];
  const float* v_mu_b = (const float*)d_in[12];
  const float* v_pro  = (const float*)d_in[13];
  const float* v_gate = (const float*)d_in[14];
  const float* o_mu_w = (const float*)d_in[15];
  const float* o_mu_b = (const float*)d_in[16];
  const float* o_pro  = (const float*)d_in[17];
  const float* o_gate = (const float*)d_in[18];

  char* w = (char*)d_ws;
  f16* WB = (f16*)w;                      // 8 x (hi 1M + lo 1M halfs) = 32MB
  const size_t WS = 2097152;
  f16* Lh  = (f16*)(w + 33554432);
  f16* Ll  = (f16*)(w + 50331648);
  f16* Qh  = (f16*)(w + 67108864);
  f16* Ql  = (f16*)(w + 83886080);
  f16* Kh  = (f16*)(w + 100663296);
  f16* Kl  = (f16*)(w + 117440512);
  f16* VTh = (f16*)(w + 134217728);
  f16* VTl = (f16*)(w + 150994944);
  float* SC = (float*)(w + 167772160);    // 64MB scores (later P hi/lo)
  float* COST = (float*)(w + 234881024);
  f16* Ath = Qh;  f16* Atl = Ql;          // attn reuses Q space

  convert_w<<<dim3(1024, 8), 256, 0, stream>>>(
      q_pro, q_mu_w, k_pro, k_mu_w, v_pro, v_mu_w, o_pro, o_mu_w, WB);
  cost_k<<<4, 256, 0, stream>>>(q_gate, k_gate, v_gate, o_gate, COST);
  layernorm_k<<<8192, 256, 0, stream>>>(x, ln_g, ln_b, Lh, Ll);

  dual_gemm_v4<0, 3><<<dim3(32, 8), 512, 0, stream>>>(
      Lh, Ll, WB, WB + 1048576, WB + WS, WB + WS + 1048576,
      q_mu_b, COST, Lh, Ll, nullptr, Qh, Ql, nullptr);
  dual_gemm_v4<0, 3><<<dim3(32, 8), 512, 0, stream>>>(
      Lh, Ll, WB + 2 * WS, WB + 2 * WS + 1048576, WB + 3 * WS, WB + 3 * WS + 1048576,
      k_mu_b, COST + 1024, Lh, Ll, nullptr, Kh, Kl, nullptr);
  // V dual writes V TRANSPOSED directly (EPI=2) -> no transpose_v dispatch
  dual_gemm_v4<2, 3><<<dim3(32, 8), 512, 0, stream>>>(
      Lh, Ll, WB + 4 * WS, WB + 4 * WS + 1048576, WB + 5 * WS, WB + 5 * WS + 1048576,
      v_mu_b, COST + 2048, Lh, Ll, nullptr, VTh, VTl, nullptr);

  scores_gemm<<<dim3(16, 16, 4), 256, 0, stream>>>(Qh, Ql, Kh, Kl, SC);
  softmax_rows<<<8192, 256, 0, stream>>>(SC);
  pv_gemm<<<dim3(16, 8, 4), 256, 0, stream>>>((const f16*)SC, VTh, VTl, Ath, Atl);

  dual_gemm_v4<1, 2><<<dim3(32, 8), 512, 0, stream>>>(
      Ath, Atl, WB + 6 * WS, WB + 6 * WS + 1048576, WB + 7 * WS, WB + 7 * WS + 1048576,
      o_mu_b, COST + 3072, Ath, Atl, x, nullptr, nullptr, (float*)d_out);
}

// Round 13
// 669.246 us; speedup vs baseline: 1.1132x; 1.1132x over previous
//
#include <hip/hip_runtime.h>
#include <hip/hip_bf16.h>
#include <cmath>
#include <cstdint>

typedef _Float16 f16;
typedef _Float16 f16x8 __attribute__((ext_vector_type(8)));
typedef float f32x4 __attribute__((ext_vector_type(4)));

#define D_ 1024
#define S_ 2048

// Split-fp16 fp32 emulation: tensor T stored as (hi, lo) f16 pair of T*1024;
// GEMM = 3 MFMA passes (hh, hl, lh).  3-pass REQUIRED wherever the result
// feeds (transitively) the rl>0 branch boundary; final O mu-GEMM -> 2-pass.
//
// FINAL CONFIG = round-7 best-total (672 us): v4 duals (512-thr, 256x128,
// dbuf 128K, reg-pipelined B-frags, one vmcnt(0)+barrier per K-step) +
// 4-wave scores/PV + LDS-tile transpose_v.  Experiments r8-r12 (16-wave
// duals, v5 attention, barrier domains, 32x32 MFMA, transpose fusion) were
// all null-to-negative on the bench total.

__device__ __forceinline__ void gload_lds16(const void* g, void* l) {
  __builtin_amdgcn_global_load_lds(
      (const __attribute__((address_space(1))) void*)(unsigned long long)(uintptr_t)g,
      (__attribute__((address_space(3))) void*)(unsigned int)(uintptr_t)l,
      16, 0, 0);
}

__device__ __forceinline__ int lds_off(int row, int cb) {
  return (row << 5) + ((cb ^ ((row >> 1) & 3)) << 3);
}

__device__ __forceinline__ void split1024(float v, f16& h, f16& l) {
  float s = v * 1024.f;  // exact
  h = (f16)s;
  l = (f16)(s - (float)h);
}

#define MFMA16(a, b, c) __builtin_amdgcn_mfma_f32_16x16x32_f16((a), (b), (c), 0, 0, 0)

// 4-wave stage helper for the attention kernels.
__device__ __forceinline__ void stage_tile(const f16* __restrict__ src, int ld,
                                           f16* lds, int wid, int lane) {
  const int r = (wid << 5) + (lane >> 2);
  const int c = (lane & 3) ^ ((r >> 1) & 3);
  const f16* g0 = src + (size_t)r * ld + (c << 3);
  gload_lds16(g0, lds + (wid << 10));
  gload_lds16(g0 + (size_t)(ld << 4), lds + (wid << 10) + 512);
}

// ------------------------------------------------------------ weights ------
__global__ __launch_bounds__(256) void convert_w(
    const float* __restrict__ s0, const float* __restrict__ s1,
    const float* __restrict__ s2, const float* __restrict__ s3,
    const float* __restrict__ s4, const float* __restrict__ s5,
    const float* __restrict__ s6, const float* __restrict__ s7,
    f16* __restrict__ dst) {
  const float* srcs[8] = {s0, s1, s2, s3, s4, s5, s6, s7};
  const float* sp = srcs[blockIdx.y];
  f16* hi = dst + (size_t)blockIdx.y * 2097152;
  f16* lo = hi + 1048576;
  const int i = (blockIdx.x * 256 + threadIdx.x) << 2;
  float4 f = *(const float4*)(sp + i);
  __align__(8) f16 h4[4], l4[4];
  split1024(f.x, h4[0], l4[0]); split1024(f.y, h4[1], l4[1]);
  split1024(f.z, h4[2], l4[2]); split1024(f.w, h4[3], l4[3]);
  *(uint2*)(hi + i) = *(uint2*)h4;
  *(uint2*)(lo + i) = *(uint2*)l4;
}

__global__ __launch_bounds__(256) void cost_k(
    const float* __restrict__ g0, const float* __restrict__ g1,
    const float* __restrict__ g2, const float* __restrict__ g3,
    float* __restrict__ cost) {
  const float* gp = blockIdx.x == 0 ? g0 : blockIdx.x == 1 ? g1
                   : blockIdx.x == 2 ? g2 : g3;
  const int t = threadIdx.x;
  float4 v = *(const float4*)(gp + (t << 2));
  float mx = fmaxf(fmaxf(fabsf(v.x), fabsf(v.y)), fmaxf(fabsf(v.z), fabsf(v.w)));
  for (int o = 32; o; o >>= 1) mx = fmaxf(mx, __shfl_xor(mx, o, 64));
  __shared__ float red[4];
  if ((t & 63) == 0) red[t >> 6] = mx;
  __syncthreads();
  mx = fmaxf(fmaxf(red[0], red[1]), fmaxf(red[2], red[3]));
  const float den = mx + 1e-9f;
  float4 o = {v.x / den, v.y / den, v.z / den, v.w / den};
  *(float4*)(cost + (blockIdx.x << 10) + (t << 2)) = o;
}

// ----------------------------------------------------------- layernorm -----
__global__ __launch_bounds__(256) void layernorm_k(
    const float* __restrict__ x, const float* __restrict__ g,
    const float* __restrict__ bta, f16* __restrict__ Lh, f16* __restrict__ Ll) {
  const int row = blockIdx.x, t = threadIdx.x;
  const float* xr = x + (size_t)row * D_;
  float4 v = *(const float4*)(xr + (t << 2));
  float s = v.x + v.y + v.z + v.w;
  float q = v.x * v.x + v.y * v.y + v.z * v.z + v.w * v.w;
  for (int o = 32; o; o >>= 1) { s += __shfl_xor(s, o, 64); q += __shfl_xor(q, o, 64); }
  __shared__ float red[8];
  const int wid = t >> 6;
  if ((t & 63) == 0) { red[wid] = s; red[4 + wid] = q; }
  __syncthreads();
  s = red[0] + red[1] + red[2] + red[3];
  q = red[4] + red[5] + red[6] + red[7];
  const float mean = s * (1.f / D_);
  const float var = q * (1.f / D_) - mean * mean;
  const float inv = 1.f / sqrtf(var + 1e-5f);
  float4 gv = *(const float4*)(g + (t << 2));
  float4 bv = *(const float4*)(bta + (t << 2));
  __align__(8) f16 h4[4], l4[4];
  split1024((v.x - mean) * inv * gv.x + bv.x, h4[0], l4[0]);
  split1024((v.y - mean) * inv * gv.y + bv.y, h4[1], l4[1]);
  split1024((v.z - mean) * inv * gv.z + bv.z, h4[2], l4[2]);
  split1024((v.w - mean) * inv * gv.w + bv.w, h4[3], l4[3]);
  const size_t off = (size_t)row * D_ + (t << 2);
  *(uint2*)(Lh + off) = *(uint2*)h4;
  *(uint2*)(Ll + off) = *(uint2*)l4;
}

// --------- dual GEMM + SPL + branch, reg-pipelined phases (v4) -------------
#define MFMA_PHASE(N, BPH, BPL, BMH, BML)                                  \
  __builtin_amdgcn_sched_barrier(0);                                       \
  __builtin_amdgcn_s_setprio(1);                                           \
  _Pragma("unroll") for (int m = 0; m < 4; ++m)                            \
      accP[m][N] = MFMA16(ah[m], (BPH), accP[m][N]);                       \
  _Pragma("unroll") for (int m = 0; m < 4; ++m)                            \
      accP[m][N] = MFMA16(ah[m], (BPL), accP[m][N]);                       \
  _Pragma("unroll") for (int m = 0; m < 4; ++m)                            \
      accP[m][N] = MFMA16(al[m], (BPH), accP[m][N]);                       \
  _Pragma("unroll") for (int m = 0; m < 4; ++m)                            \
      accM[m][N] = MFMA16(ah[m], (BMH), accM[m][N]);                       \
  _Pragma("unroll") for (int m = 0; m < 4; ++m)                            \
      accM[m][N] = MFMA16(ah[m], (BML), accM[m][N]);                       \
  if (MUP == 3) {                                                          \
    _Pragma("unroll") for (int m = 0; m < 4; ++m)                          \
        accM[m][N] = MFMA16(al[m], (BMH), accM[m][N]);                     \
  }                                                                        \
  __builtin_amdgcn_s_setprio(0);

template <int EPI, int MUP>
__global__ __launch_bounds__(512, 1) void dual_gemm_v4(
    const f16* __restrict__ Ah, const f16* __restrict__ Al,
    const f16* __restrict__ Wph, const f16* __restrict__ Wpl,
    const f16* __restrict__ Wmh, const f16* __restrict__ Wml,
    const float* __restrict__ bias, const float* __restrict__ cost,
    const f16* __restrict__ passh, const f16* __restrict__ passl,
    const float* __restrict__ xres, f16* __restrict__ outh,
    f16* __restrict__ outl, float* __restrict__ outf) {
  __shared__ __align__(16) f16 smem[65536];
  const int tid = threadIdx.x, wid = tid >> 6, lane = tid & 63;
  const int row0 = blockIdx.x << 8, col0 = blockIdx.y << 7;
  const int wr = (wid >> 1) << 6, wc = (wid & 1) << 6;
  const int arow = lane & 15, cbk = lane >> 4;

  const int sr = tid >> 2;
  const int sc = ((tid & 3) ^ ((sr >> 1) & 3)) << 3;
  const int wbase = wid << 9;

  const f16* pA0 = Ah + (size_t)(row0 + sr) * D_ + sc;
  const f16* pA1 = Ah + (size_t)(row0 + 128 + sr) * D_ + sc;
  const f16* pL0 = Al + (size_t)(row0 + sr) * D_ + sc;
  const f16* pL1 = Al + (size_t)(row0 + 128 + sr) * D_ + sc;
  const f16* pPh = Wph + (size_t)(col0 + sr) * D_ + sc;
  const f16* pPl = Wpl + (size_t)(col0 + sr) * D_ + sc;
  const f16* pMh = Wmh + (size_t)(col0 + sr) * D_ + sc;
  const f16* pMl = Wml + (size_t)(col0 + sr) * D_ + sc;

  const f32x4 zero = {0.f, 0.f, 0.f, 0.f};
  f32x4 accP[4][4], accM[4][4];
#pragma unroll
  for (int m = 0; m < 4; ++m)
#pragma unroll
    for (int n = 0; n < 4; ++n) { accP[m][n] = zero; accM[m][n] = zero; }

  int aoff[4], boff[4];
#pragma unroll
  for (int m = 0; m < 4; ++m) aoff[m] = lds_off(wr + m * 16 + arow, cbk);
#pragma unroll
  for (int n = 0; n < 4; ++n) boff[n] = lds_off(wc + n * 16 + arow, cbk);

  {
    f16* b = smem;
    gload_lds16(pA0, b + wbase);          gload_lds16(pA1, b + 4096 + wbase);
    gload_lds16(pL0, b + 8192 + wbase);   gload_lds16(pL1, b + 12288 + wbase);
    gload_lds16(pPh, b + 16384 + wbase);  gload_lds16(pPl, b + 20480 + wbase);
    gload_lds16(pMh, b + 24576 + wbase);  gload_lds16(pMl, b + 28672 + wbase);
  }
  asm volatile("s_waitcnt vmcnt(0)" ::: "memory");
  __builtin_amdgcn_s_barrier();
  __builtin_amdgcn_sched_barrier(0);

  int cur = 0;
  for (int t = 0; t < 32; ++t) {
    const f16* bb = smem + (cur << 15);
    f16* nb = smem + ((cur ^ 1) << 15);
    const int kn = (t < 31) ? ((t + 1) << 5) : 0;

    f16x8 ah[4], al[4];
#pragma unroll
    for (int m = 0; m < 4; ++m) {
      ah[m] = *(const f16x8*)&bb[aoff[m]];
      al[m] = *(const f16x8*)&bb[8192 + aoff[m]];
    }
    f16x8 xph = *(const f16x8*)&bb[16384 + boff[0]];
    f16x8 xpl = *(const f16x8*)&bb[20480 + boff[0]];
    f16x8 xmh = *(const f16x8*)&bb[24576 + boff[0]];
    f16x8 xml = *(const f16x8*)&bb[28672 + boff[0]];
    f16x8 yph = *(const f16x8*)&bb[16384 + boff[1]];
    f16x8 ypl = *(const f16x8*)&bb[20480 + boff[1]];
    f16x8 ymh = *(const f16x8*)&bb[24576 + boff[1]];
    f16x8 yml = *(const f16x8*)&bb[28672 + boff[1]];
    gload_lds16(pA0 + kn, nb + wbase);
    gload_lds16(pA1 + kn, nb + 4096 + wbase);
    MFMA_PHASE(0, xph, xpl, xmh, xml)

    xph = *(const f16x8*)&bb[16384 + boff[2]];
    xpl = *(const f16x8*)&bb[20480 + boff[2]];
    xmh = *(const f16x8*)&bb[24576 + boff[2]];
    xml = *(const f16x8*)&bb[28672 + boff[2]];
    gload_lds16(pL0 + kn, nb + 8192 + wbase);
    gload_lds16(pL1 + kn, nb + 12288 + wbase);
    MFMA_PHASE(1, yph, ypl, ymh, yml)

    yph = *(const f16x8*)&bb[16384 + boff[3]];
    ypl = *(const f16x8*)&bb[20480 + boff[3]];
    ymh = *(const f16x8*)&bb[24576 + boff[3]];
    yml = *(const f16x8*)&bb[28672 + boff[3]];
    gload_lds16(pPh + kn, nb + 16384 + wbase);
    gload_lds16(pPl + kn, nb + 20480 + wbase);
    MFMA_PHASE(2, xph, xpl, xmh, xml)

    gload_lds16(pMh + kn, nb + 24576 + wbase);
    gload_lds16(pMl + kn, nb + 28672 + wbase);
    MFMA_PHASE(3, yph, ypl, ymh, yml)

    asm volatile("s_waitcnt vmcnt(0)" ::: "memory");
    __builtin_amdgcn_s_barrier();
    __builtin_amdgcn_sched_barrier(0);
    cur ^= 1;
  }

  // acc = 2^20 * true.  match = acc*2^-25 (incl /32); pre = acc*2^-20.
#pragma unroll
  for (int m = 0; m < 4; ++m) {
    const int rb = row0 + wr + m * 16 + ((lane >> 4) << 2);
#pragma unroll
    for (int n = 0; n < 4; ++n) {
      const int col = col0 + wc + n * 16 + (lane & 15);
      const float cb2 = cost[col], bbv = bias[col];
#pragma unroll
      for (int j = 0; j < 4; ++j) {
        const size_t off = (size_t)(rb + j) * D_ + col;
        const float match = accP[m][n][j] * (1.f / 33554432.f);
        const float pre = accM[m][n][j] * (1.f / 1048576.f) + bbv;
        const float comp = pre / (1.f + expf(-pre));
        const float rl = match - cb2;
        float ov;
        if (rl > 0.f) ov = comp * rl;
        else ov = ((float)passh[off] + (float)passl[off]) * (1.f / 1024.f);
        if (EPI == 0) {
          f16 h, l; split1024(ov, h, l);
          outh[off] = h; outl[off] = l;
        } else {
          outf[off] = xres[off] + ov;
        }
      }
    }
  }
}

// ------------------------------------------------------- V transpose -------
__global__ __launch_bounds__(256) void transpose_v(
    const f16* __restrict__ Vh, const f16* __restrict__ Vl,
    f16* __restrict__ VTh, f16* __restrict__ VTl) {
  const int iz = blockIdx.z, b = iz & 3;
  const f16* src = (iz >> 2) ? Vl : Vh;
  f16* dst = (iz >> 2) ? VTl : VTh;
  const int d0 = blockIdx.x << 6, s0 = blockIdx.y << 6;
  __shared__ f16 tl[64][65];
  const int c = threadIdx.x & 63, r4 = threadIdx.x >> 6;
  const f16* vb = src + (size_t)b * S_ * D_;
#pragma unroll
  for (int i = 0; i < 16; ++i) {
    const int sr = (r4 << 4) + i;
    tl[sr][c] = vb[(size_t)(s0 + sr) * D_ + d0 + c];
  }
  __syncthreads();
  f16* db = dst + (size_t)b * D_ * S_;
#pragma unroll
  for (int i = 0; i < 16; ++i) {
    const int dr = (r4 << 4) + i;
    db[(size_t)(d0 + dr) * S_ + s0 + c] = tl[c][dr];
  }
}

// ------------------------------------------------- scores = q k^T / 32 -----
__global__ __launch_bounds__(256, 2) void scores_gemm(
    const f16* __restrict__ Qh, const f16* __restrict__ Ql,
    const f16* __restrict__ Kh, const f16* __restrict__ Kl,
    float* __restrict__ SC) {
  const int rt = blockIdx.x, ct = blockIdx.y, b = blockIdx.z;
  if (ct > rt) return;
  __shared__ __align__(16) f16 lQh[4096], lQl[4096], lKh[4096], lKl[4096];
  const int tid = threadIdx.x, wid = tid >> 6, lane = tid & 63;
  const int row0 = rt << 7, col0 = ct << 7;
  const int wr = (wid >> 1) << 6, wc = (wid & 1) << 6;
  const int arow = lane & 15, cb = lane >> 4;
  const f32x4 zero = {0.f, 0.f, 0.f, 0.f};
  f32x4 acc[4][4];
#pragma unroll
  for (int m = 0; m < 4; ++m)
#pragma unroll
    for (int n = 0; n < 4; ++n) acc[m][n] = zero;
  const f16* Qhb = Qh + ((size_t)b * S_ + row0) * D_;
  const f16* Qlb = Ql + ((size_t)b * S_ + row0) * D_;
  const f16* Khb = Kh + ((size_t)b * S_ + col0) * D_;
  const f16* Klb = Kl + ((size_t)b * S_ + col0) * D_;
  for (int k = 0; k < D_; k += 32) {
    stage_tile(Qhb + k, D_, lQh, wid, lane);
    stage_tile(Qlb + k, D_, lQl, wid, lane);
    stage_tile(Khb + k, D_, lKh, wid, lane);
    stage_tile(Klb + k, D_, lKl, wid, lane);
    __syncthreads();
    f16x8 bh[4], bl[4];
#pragma unroll
    for (int n = 0; n < 4; ++n) {
      const int bo = lds_off(wc + n * 16 + arow, cb);
      bh[n] = *(const f16x8*)&lKh[bo];
      bl[n] = *(const f16x8*)&lKl[bo];
    }
#pragma unroll
    for (int m = 0; m < 4; ++m) {
      const int ao = lds_off(wr + m * 16 + arow, cb);
      f16x8 ah = *(const f16x8*)&lQh[ao];
      f16x8 al = *(const f16x8*)&lQl[ao];
#pragma unroll
      for (int n = 0; n < 4; ++n) {
        acc[m][n] = MFMA16(ah, bh[n], acc[m][n]);
        acc[m][n] = MFMA16(ah, bl[n], acc[m][n]);
        acc[m][n] = MFMA16(al, bh[n], acc[m][n]);
      }
    }
    __syncthreads();
  }
  float* scb = SC + (size_t)b * S_ * S_;
#pragma unroll
  for (int m = 0; m < 4; ++m) {
    const int rb = row0 + wr + m * 16 + ((lane >> 4) << 2);
#pragma unroll
    for (int n = 0; n < 4; ++n) {
      const int col = col0 + wc + n * 16 + (lane & 15);
#pragma unroll
      for (int j = 0; j < 4; ++j)
        scb[(size_t)(rb + j) * S_ + col] = acc[m][n][j] * (1.f / 33554432.f);
    }
  }
}

// --------------------------- softmax (causal) + in-place hi/lo f16 pack ----
__global__ __launch_bounds__(256) void softmax_rows(float* __restrict__ SC) {
  const int r = blockIdx.x;
  const int s = r & 2047;
  float* rowf = SC + (size_t)r * S_;
  const int t = threadIdx.x, c0 = t << 3;
  float f[8];
  float4 u0 = *(const float4*)(rowf + c0);
  float4 u1 = *(const float4*)(rowf + c0 + 4);
  f[0] = u0.x; f[1] = u0.y; f[2] = u0.z; f[3] = u0.w;
  f[4] = u1.x; f[5] = u1.y; f[6] = u1.z; f[7] = u1.w;
  float mx = -3.0e38f;
#pragma unroll
  for (int j = 0; j < 8; ++j)
    if (c0 + j <= s) mx = fmaxf(mx, f[j]);
  for (int o = 32; o; o >>= 1) mx = fmaxf(mx, __shfl_xor(mx, o, 64));
  __shared__ float red[8];
  const int wid = t >> 6;
  if ((t & 63) == 0) red[wid] = mx;
  __syncthreads();
  mx = fmaxf(fmaxf(red[0], red[1]), fmaxf(red[2], red[3]));
  float e[8];
  float sum = 0.f;
#pragma unroll
  for (int j = 0; j < 8; ++j) {
    e[j] = (c0 + j <= s) ? expf(f[j] - mx) : 0.f;
    sum += e[j];
  }
  for (int o = 32; o; o >>= 1) sum += __shfl_xor(sum, o, 64);
  if ((t & 63) == 0) red[4 + wid] = sum;
  __syncthreads();
  sum = red[4] + red[5] + red[6] + red[7];
  f16* rowh = (f16*)rowf;
  __align__(16) f16 ph[8], pl[8];
#pragma unroll
  for (int j = 0; j < 8; ++j) {
    float p = (e[j] / sum) * 2048.f;
    ph[j] = (f16)p;
    pl[j] = (f16)(p - (float)ph[j]);
  }
  *(uint4*)(rowh + c0) = *(uint4*)ph;
  *(uint4*)(rowh + 2048 + c0) = *(uint4*)pl;
}

// --------------------------------------------------------- attn = P V ------
__global__ __launch_bounds__(256, 2) void pv_gemm(
    const f16* __restrict__ P, const f16* __restrict__ VTh,
    const f16* __restrict__ VTl, f16* __restrict__ Ath, f16* __restrict__ Atl) {
  const int rt = blockIdx.x, ct = blockIdx.y, b = blockIdx.z;
  __shared__ __align__(16) f16 lPh[4096], lPl[4096], lVh[4096], lVl[4096];
  const int tid = threadIdx.x, wid = tid >> 6, lane = tid & 63;
  const int row0 = rt << 7, col0 = ct << 7;
  const int wr = (wid >> 1) << 6, wc = (wid & 1) << 6;
  const int arow = lane & 15, cb = lane >> 4;
  const f32x4 zero = {0.f, 0.f, 0.f, 0.f};
  f32x4 acc[4][4];
#pragma unroll
  for (int m = 0; m < 4; ++m)
#pragma unroll
    for (int n = 0; n < 4; ++n) acc[m][n] = zero;
  const f16* Pb = P + ((size_t)b * S_ + row0) * 4096;
  const f16* Vhb = VTh + (size_t)b * D_ * S_ + (size_t)col0 * S_;
  const f16* Vlb = VTl + (size_t)b * D_ * S_ + (size_t)col0 * S_;
  const int kend = (rt + 1) << 7;
  for (int k = 0; k < kend; k += 32) {
    stage_tile(Pb + k, 4096, lPh, wid, lane);
    stage_tile(Pb + 2048 + k, 4096, lPl, wid, lane);
    stage_tile(Vhb + k, S_, lVh, wid, lane);
    stage_tile(Vlb + k, S_, lVl, wid, lane);
    __syncthreads();
    f16x8 bh[4], bl[4];
#pragma unroll
    for (int n = 0; n < 4; ++n) {
      const int bo = lds_off(wc + n * 16 + arow, cb);
      bh[n] = *(const f16x8*)&lVh[bo];
      bl[n] = *(const f16x8*)&lVl[bo];
    }
#pragma unroll
    for (int m = 0; m < 4; ++m) {
      const int ao = lds_off(wr + m * 16 + arow, cb);
      f16x8 ah = *(const f16x8*)&lPh[ao];
      f16x8 al = *(const f16x8*)&lPl[ao];
#pragma unroll
      for (int n = 0; n < 4; ++n) {
        acc[m][n] = MFMA16(ah, bh[n], acc[m][n]);
        acc[m][n] = MFMA16(ah, bl[n], acc[m][n]);
        acc[m][n] = MFMA16(al, bh[n], acc[m][n]);
      }
    }
    __syncthreads();
  }
  // acc = 2048*1024 * attn  -> attn = acc * 2^-21
#pragma unroll
  for (int m = 0; m < 4; ++m) {
    const int rb = row0 + wr + m * 16 + ((lane >> 4) << 2);
#pragma unroll
    for (int n = 0; n < 4; ++n) {
      const int col = col0 + wc + n * 16 + (lane & 15);
#pragma unroll
      for (int j = 0; j < 4; ++j) {
        const float at = acc[m][n][j] * (1.f / 2097152.f);
        const size_t off = ((size_t)b * S_ + rb + j) * D_ + col;
        f16 h, l; split1024(at, h, l);
        Ath[off] = h; Atl[off] = l;
      }
    }
  }
}

// ---------------------------------------------------------------- host -----
extern "C" void kernel_launch(void* const* d_in, const int* in_sizes, int n_in,
                              void* d_out, int out_size, void* d_ws, size_t ws_size,
                              hipStream_t stream) {
  (void)in_sizes; (void)n_in; (void)out_size; (void)ws_size;
  const float* x      = (const float*)d_in[0];
  const float* ln_g   = (const float*)d_in[1];
  const float* ln_b   = (const float*)d_in[2];
  const float* q_mu_w = (const float*)d_in[3];
  const float* q_mu_b = (const float*)d_in[4];
  const float* q_pro  = (const float*)d_in[5];
  const float* q_gate = (const float*)d_in[6];
  const float* k_mu_w = (const float*)d_in[7];
  const float* k_mu_b = (const float*)d_in[8];
  const float* k_pro  = (const float*)d_in[9];
  const float* k_gate = (const float*)d_in[10];
  const float* v_mu_w = (const float*)d_in[11];
  const float* v_mu_b = (const float*)d_in[12];
  const float* v_pro  = (const float*)d_in[13];
  const float* v_gate = (const float*)d_in[14];
  const float* o_mu_w = (const float*)d_in[15];
  const float* o_mu_b = (const float*)d_in[16];
  const float* o_pro  = (const float*)d_in[17];
  const float* o_gate = (const float*)d_in[18];

  char* w = (char*)d_ws;
  f16* WB = (f16*)w;                      // 8 x (hi 1M + lo 1M halfs) = 32MB
  const size_t WS = 2097152;
  f16* Lh  = (f16*)(w + 33554432);
  f16* Ll  = (f16*)(w + 50331648);
  f16* Qh  = (f16*)(w + 67108864);
  f16* Ql  = (f16*)(w + 83886080);
  f16* Kh  = (f16*)(w + 100663296);
  f16* Kl  = (f16*)(w + 117440512);
  f16* VTh = (f16*)(w + 134217728);
  f16* VTl = (f16*)(w + 150994944);
  float* SC = (float*)(w + 167772160);    // 64MB scores (later P hi/lo)
  float* COST = (float*)(w + 234881024);
  f16* Vh = (f16*)SC;                     // temp V before transpose
  f16* Vl = (f16*)(w + 184549376);
  f16* Ath = Qh;  f16* Atl = Ql;          // attn reuses Q space

  convert_w<<<dim3(1024, 8), 256, 0, stream>>>(
      q_pro, q_mu_w, k_pro, k_mu_w, v_pro, v_mu_w, o_pro, o_mu_w, WB);
  cost_k<<<4, 256, 0, stream>>>(q_gate, k_gate, v_gate, o_gate, COST);
  layernorm_k<<<8192, 256, 0, stream>>>(x, ln_g, ln_b, Lh, Ll);

  dual_gemm_v4<0, 3><<<dim3(32, 8), 512, 0, stream>>>(
      Lh, Ll, WB, WB + 1048576, WB + WS, WB + WS + 1048576,
      q_mu_b, COST, Lh, Ll, nullptr, Qh, Ql, nullptr);
  dual_gemm_v4<0, 3><<<dim3(32, 8), 512, 0, stream>>>(
      Lh, Ll, WB + 2 * WS, WB + 2 * WS + 1048576, WB + 3 * WS, WB + 3 * WS + 1048576,
      k_mu_b, COST + 1024, Lh, Ll, nullptr, Kh, Kl, nullptr);
  dual_gemm_v4<0, 3><<<dim3(32, 8), 512, 0, stream>>>(
      Lh, Ll, WB + 4 * WS, WB + 4 * WS + 1048576, WB + 5 * WS, WB + 5 * WS + 1048576,
      v_mu_b, COST + 2048, Lh, Ll, nullptr, Vh, Vl, nullptr);

  transpose_v<<<dim3(16, 32, 8), 256, 0, stream>>>(Vh, Vl, VTh, VTl);
  scores_gemm<<<dim3(16, 16, 4), 256, 0, stream>>>(Qh, Ql, Kh, Kl, SC);
  softmax_rows<<<8192, 256, 0, stream>>>(SC);
  pv_gemm<<<dim3(16, 8, 4), 256, 0, stream>>>((const f16*)SC, VTh, VTl, Ath, Atl);

  dual_gemm_v4<1, 2><<<dim3(32, 8), 512, 0, stream>>>(
      Ath, Atl, WB + 6 * WS, WB + 6 * WS + 1048576, WB + 7 * WS, WB + 7 * WS + 1048576,
      o_mu_b, COST + 3072, Ath, Atl, x, nullptr, nullptr, (float*)d_out);
}

// Round 14
// 666.573 us; speedup vs baseline: 1.1176x; 1.0040x over previous
//
#include <hip/hip_runtime.h>
#include <hip/hip_bf16.h>
#include <cmath>
#include <cstdint>

typedef _Float16 f16;
typedef _Float16 f16x8 __attribute__((ext_vector_type(8)));
typedef float f32x4 __attribute__((ext_vector_type(4)));

#define D_ 1024
#define S_ 2048

// Split-fp16 fp32 emulation: tensor T stored as (hi, lo) f16 pair of T*1024;
// GEMM = 3 MFMA passes (hh, hl, lh).  3-pass REQUIRED wherever the result
// feeds (transitively) the rl>0 branch boundary; final O mu-GEMM -> 2-pass.
//
// Config = r13 best (669 us) + QKV duals fused into ONE dispatch (grid 32x24,
// branch = blockIdx.y>>3, block-uniform pointer select) -- removes 2 dispatch
// gaps and packs cross-branch tails.  Per-block math bit-identical to v4.

__device__ __forceinline__ void gload_lds16(const void* g, void* l) {
  __builtin_amdgcn_global_load_lds(
      (const __attribute__((address_space(1))) void*)(unsigned long long)(uintptr_t)g,
      (__attribute__((address_space(3))) void*)(unsigned int)(uintptr_t)l,
      16, 0, 0);
}

__device__ __forceinline__ int lds_off(int row, int cb) {
  return (row << 5) + ((cb ^ ((row >> 1) & 3)) << 3);
}

__device__ __forceinline__ void split1024(float v, f16& h, f16& l) {
  float s = v * 1024.f;  // exact
  h = (f16)s;
  l = (f16)(s - (float)h);
}

#define MFMA16(a, b, c) __builtin_amdgcn_mfma_f32_16x16x32_f16((a), (b), (c), 0, 0, 0)

// 4-wave stage helper for the attention kernels.
__device__ __forceinline__ void stage_tile(const f16* __restrict__ src, int ld,
                                           f16* lds, int wid, int lane) {
  const int r = (wid << 5) + (lane >> 2);
  const int c = (lane & 3) ^ ((r >> 1) & 3);
  const f16* g0 = src + (size_t)r * ld + (c << 3);
  gload_lds16(g0, lds + (wid << 10));
  gload_lds16(g0 + (size_t)(ld << 4), lds + (wid << 10) + 512);
}

// ------------------------------------------------------------ weights ------
__global__ __launch_bounds__(256) void convert_w(
    const float* __restrict__ s0, const float* __restrict__ s1,
    const float* __restrict__ s2, const float* __restrict__ s3,
    const float* __restrict__ s4, const float* __restrict__ s5,
    const float* __restrict__ s6, const float* __restrict__ s7,
    f16* __restrict__ dst) {
  const float* srcs[8] = {s0, s1, s2, s3, s4, s5, s6, s7};
  const float* sp = srcs[blockIdx.y];
  f16* hi = dst + (size_t)blockIdx.y * 2097152;
  f16* lo = hi + 1048576;
  const int i = (blockIdx.x * 256 + threadIdx.x) << 2;
  float4 f = *(const float4*)(sp + i);
  __align__(8) f16 h4[4], l4[4];
  split1024(f.x, h4[0], l4[0]); split1024(f.y, h4[1], l4[1]);
  split1024(f.z, h4[2], l4[2]); split1024(f.w, h4[3], l4[3]);
  *(uint2*)(hi + i) = *(uint2*)h4;
  *(uint2*)(lo + i) = *(uint2*)l4;
}

__global__ __launch_bounds__(256) void cost_k(
    const float* __restrict__ g0, const float* __restrict__ g1,
    const float* __restrict__ g2, const float* __restrict__ g3,
    float* __restrict__ cost) {
  const float* gp = blockIdx.x == 0 ? g0 : blockIdx.x == 1 ? g1
                   : blockIdx.x == 2 ? g2 : g3;
  const int t = threadIdx.x;
  float4 v = *(const float4*)(gp + (t << 2));
  float mx = fmaxf(fmaxf(fabsf(v.x), fabsf(v.y)), fmaxf(fabsf(v.z), fabsf(v.w)));
  for (int o = 32; o; o >>= 1) mx = fmaxf(mx, __shfl_xor(mx, o, 64));
  __shared__ float red[4];
  if ((t & 63) == 0) red[t >> 6] = mx;
  __syncthreads();
  mx = fmaxf(fmaxf(red[0], red[1]), fmaxf(red[2], red[3]));
  const float den = mx + 1e-9f;
  float4 o = {v.x / den, v.y / den, v.z / den, v.w / den};
  *(float4*)(cost + (blockIdx.x << 10) + (t << 2)) = o;
}

// ----------------------------------------------------------- layernorm -----
__global__ __launch_bounds__(256) void layernorm_k(
    const float* __restrict__ x, const float* __restrict__ g,
    const float* __restrict__ bta, f16* __restrict__ Lh, f16* __restrict__ Ll) {
  const int row = blockIdx.x, t = threadIdx.x;
  const float* xr = x + (size_t)row * D_;
  float4 v = *(const float4*)(xr + (t << 2));
  float s = v.x + v.y + v.z + v.w;
  float q = v.x * v.x + v.y * v.y + v.z * v.z + v.w * v.w;
  for (int o = 32; o; o >>= 1) { s += __shfl_xor(s, o, 64); q += __shfl_xor(q, o, 64); }
  __shared__ float red[8];
  const int wid = t >> 6;
  if ((t & 63) == 0) { red[wid] = s; red[4 + wid] = q; }
  __syncthreads();
  s = red[0] + red[1] + red[2] + red[3];
  q = red[4] + red[5] + red[6] + red[7];
  const float mean = s * (1.f / D_);
  const float var = q * (1.f / D_) - mean * mean;
  const float inv = 1.f / sqrtf(var + 1e-5f);
  float4 gv = *(const float4*)(g + (t << 2));
  float4 bv = *(const float4*)(bta + (t << 2));
  __align__(8) f16 h4[4], l4[4];
  split1024((v.x - mean) * inv * gv.x + bv.x, h4[0], l4[0]);
  split1024((v.y - mean) * inv * gv.y + bv.y, h4[1], l4[1]);
  split1024((v.z - mean) * inv * gv.z + bv.z, h4[2], l4[2]);
  split1024((v.w - mean) * inv * gv.w + bv.w, h4[3], l4[3]);
  const size_t off = (size_t)row * D_ + (t << 2);
  *(uint2*)(Lh + off) = *(uint2*)h4;
  *(uint2*)(Ll + off) = *(uint2*)l4;
}

// --------- dual GEMM + SPL + branch, reg-pipelined phases (v4) -------------
#define MFMA_PHASE(N, BPH, BPL, BMH, BML)                                  \
  __builtin_amdgcn_sched_barrier(0);                                       \
  __builtin_amdgcn_s_setprio(1);                                           \
  _Pragma("unroll") for (int m = 0; m < 4; ++m)                            \
      accP[m][N] = MFMA16(ah[m], (BPH), accP[m][N]);                       \
  _Pragma("unroll") for (int m = 0; m < 4; ++m)                            \
      accP[m][N] = MFMA16(ah[m], (BPL), accP[m][N]);                       \
  _Pragma("unroll") for (int m = 0; m < 4; ++m)                            \
      accP[m][N] = MFMA16(al[m], (BPH), accP[m][N]);                       \
  _Pragma("unroll") for (int m = 0; m < 4; ++m)                            \
      accM[m][N] = MFMA16(ah[m], (BMH), accM[m][N]);                       \
  _Pragma("unroll") for (int m = 0; m < 4; ++m)                            \
      accM[m][N] = MFMA16(ah[m], (BML), accM[m][N]);                       \
  if (MUP == 3) {                                                          \
    _Pragma("unroll") for (int m = 0; m < 4; ++m)                          \
        accM[m][N] = MFMA16(al[m], (BMH), accM[m][N]);                     \
  }                                                                        \
  __builtin_amdgcn_s_setprio(0);

// Shared body: computes one 256x128 tile of the dual GEMM for given operand
// pointers; EPI/MUP as before.
template <int EPI, int MUP>
__device__ __forceinline__ void dual_body(
    const f16* __restrict__ Ah, const f16* __restrict__ Al,
    const f16* __restrict__ Wph, const f16* __restrict__ Wpl,
    const f16* __restrict__ Wmh, const f16* __restrict__ Wml,
    const float* __restrict__ bias, const float* __restrict__ cost,
    const f16* __restrict__ passh, const f16* __restrict__ passl,
    const float* __restrict__ xres, f16* __restrict__ outh,
    f16* __restrict__ outl, float* __restrict__ outf,
    f16* smem, int row0, int col0) {
  const int tid = threadIdx.x, wid = tid >> 6, lane = tid & 63;
  const int wr = (wid >> 1) << 6, wc = (wid & 1) << 6;
  const int arow = lane & 15, cbk = lane >> 4;

  const int sr = tid >> 2;
  const int sc = ((tid & 3) ^ ((sr >> 1) & 3)) << 3;
  const int wbase = wid << 9;

  const f16* pA0 = Ah + (size_t)(row0 + sr) * D_ + sc;
  const f16* pA1 = Ah + (size_t)(row0 + 128 + sr) * D_ + sc;
  const f16* pL0 = Al + (size_t)(row0 + sr) * D_ + sc;
  const f16* pL1 = Al + (size_t)(row0 + 128 + sr) * D_ + sc;
  const f16* pPh = Wph + (size_t)(col0 + sr) * D_ + sc;
  const f16* pPl = Wpl + (size_t)(col0 + sr) * D_ + sc;
  const f16* pMh = Wmh + (size_t)(col0 + sr) * D_ + sc;
  const f16* pMl = Wml + (size_t)(col0 + sr) * D_ + sc;

  const f32x4 zero = {0.f, 0.f, 0.f, 0.f};
  f32x4 accP[4][4], accM[4][4];
#pragma unroll
  for (int m = 0; m < 4; ++m)
#pragma unroll
    for (int n = 0; n < 4; ++n) { accP[m][n] = zero; accM[m][n] = zero; }

  int aoff[4], boff[4];
#pragma unroll
  for (int m = 0; m < 4; ++m) aoff[m] = lds_off(wr + m * 16 + arow, cbk);
#pragma unroll
  for (int n = 0; n < 4; ++n) boff[n] = lds_off(wc + n * 16 + arow, cbk);

  {
    f16* b = smem;
    gload_lds16(pA0, b + wbase);          gload_lds16(pA1, b + 4096 + wbase);
    gload_lds16(pL0, b + 8192 + wbase);   gload_lds16(pL1, b + 12288 + wbase);
    gload_lds16(pPh, b + 16384 + wbase);  gload_lds16(pPl, b + 20480 + wbase);
    gload_lds16(pMh, b + 24576 + wbase);  gload_lds16(pMl, b + 28672 + wbase);
  }
  asm volatile("s_waitcnt vmcnt(0)" ::: "memory");
  __builtin_amdgcn_s_barrier();
  __builtin_amdgcn_sched_barrier(0);

  int cur = 0;
  for (int t = 0; t < 32; ++t) {
    const f16* bb = smem + (cur << 15);
    f16* nb = smem + ((cur ^ 1) << 15);
    const int kn = (t < 31) ? ((t + 1) << 5) : 0;

    f16x8 ah[4], al[4];
#pragma unroll
    for (int m = 0; m < 4; ++m) {
      ah[m] = *(const f16x8*)&bb[aoff[m]];
      al[m] = *(const f16x8*)&bb[8192 + aoff[m]];
    }
    f16x8 xph = *(const f16x8*)&bb[16384 + boff[0]];
    f16x8 xpl = *(const f16x8*)&bb[20480 + boff[0]];
    f16x8 xmh = *(const f16x8*)&bb[24576 + boff[0]];
    f16x8 xml = *(const f16x8*)&bb[28672 + boff[0]];
    f16x8 yph = *(const f16x8*)&bb[16384 + boff[1]];
    f16x8 ypl = *(const f16x8*)&bb[20480 + boff[1]];
    f16x8 ymh = *(const f16x8*)&bb[24576 + boff[1]];
    f16x8 yml = *(const f16x8*)&bb[28672 + boff[1]];
    gload_lds16(pA0 + kn, nb + wbase);
    gload_lds16(pA1 + kn, nb + 4096 + wbase);
    MFMA_PHASE(0, xph, xpl, xmh, xml)

    xph = *(const f16x8*)&bb[16384 + boff[2]];
    xpl = *(const f16x8*)&bb[20480 + boff[2]];
    xmh = *(const f16x8*)&bb[24576 + boff[2]];
    xml = *(const f16x8*)&bb[28672 + boff[2]];
    gload_lds16(pL0 + kn, nb + 8192 + wbase);
    gload_lds16(pL1 + kn, nb + 12288 + wbase);
    MFMA_PHASE(1, yph, ypl, ymh, yml)

    yph = *(const f16x8*)&bb[16384 + boff[3]];
    ypl = *(const f16x8*)&bb[20480 + boff[3]];
    ymh = *(const f16x8*)&bb[24576 + boff[3]];
    yml = *(const f16x8*)&bb[28672 + boff[3]];
    gload_lds16(pPh + kn, nb + 16384 + wbase);
    gload_lds16(pPl + kn, nb + 20480 + wbase);
    MFMA_PHASE(2, xph, xpl, xmh, xml)

    gload_lds16(pMh + kn, nb + 24576 + wbase);
    gload_lds16(pMl + kn, nb + 28672 + wbase);
    MFMA_PHASE(3, yph, ypl, ymh, yml)

    asm volatile("s_waitcnt vmcnt(0)" ::: "memory");
    __builtin_amdgcn_s_barrier();
    __builtin_amdgcn_sched_barrier(0);
    cur ^= 1;
  }

  // acc = 2^20 * true.  match = acc*2^-25 (incl /32); pre = acc*2^-20.
#pragma unroll
  for (int m = 0; m < 4; ++m) {
    const int rb = row0 + wr + m * 16 + ((lane >> 4) << 2);
#pragma unroll
    for (int n = 0; n < 4; ++n) {
      const int col = col0 + wc + n * 16 + (lane & 15);
      const float cb2 = cost[col], bbv = bias[col];
#pragma unroll
      for (int j = 0; j < 4; ++j) {
        const size_t off = (size_t)(rb + j) * D_ + col;
        const float match = accP[m][n][j] * (1.f / 33554432.f);
        const float pre = accM[m][n][j] * (1.f / 1048576.f) + bbv;
        const float comp = pre / (1.f + expf(-pre));
        const float rl = match - cb2;
        float ov;
        if (rl > 0.f) ov = comp * rl;
        else ov = ((float)passh[off] + (float)passl[off]) * (1.f / 1024.f);
        if (EPI == 0) {
          f16 h, l; split1024(ov, h, l);
          outh[off] = h; outl[off] = l;
        } else {
          outf[off] = xres[off] + ov;
        }
      }
    }
  }
}

// Fused Q/K/V duals: one dispatch, grid (32, 24); branch = blockIdx.y>>3.
__global__ __launch_bounds__(512, 1) void dual_gemm_qkv(
    const f16* __restrict__ Ah, const f16* __restrict__ Al,
    const f16* __restrict__ WB,
    const float* __restrict__ qb, const float* __restrict__ kb,
    const float* __restrict__ vb, const float* __restrict__ COST,
    f16* __restrict__ Qh, f16* __restrict__ Ql,
    f16* __restrict__ Kh, f16* __restrict__ Kl,
    f16* __restrict__ Vh, f16* __restrict__ Vl) {
  __shared__ __align__(16) f16 smem[65536];
  const int br = blockIdx.y >> 3;
  const int row0 = blockIdx.x << 8;
  const int col0 = (blockIdx.y & 7) << 7;
  // WB blocks of 2097152 halfs: [q_pro, q_mu, k_pro, k_mu, v_pro, v_mu, ...]
  const f16* Wph = WB + (size_t)br * 4194304;
  const f16* Wpl = Wph + 1048576;
  const f16* Wmh = Wph + 2097152;
  const f16* Wml = Wph + 3145728;
  const float* bias = br == 0 ? qb : br == 1 ? kb : vb;
  const float* cost = COST + (br << 10);
  f16* outh = br == 0 ? Qh : br == 1 ? Kh : Vh;
  f16* outl = br == 0 ? Ql : br == 1 ? Kl : Vl;
  dual_body<0, 3>(Ah, Al, Wph, Wpl, Wmh, Wml, bias, cost, Ah, Al, nullptr,
                  outh, outl, nullptr, smem, row0, col0);
}

// O-branch dual (EPI=1, 2-pass mu), unchanged.
__global__ __launch_bounds__(512, 1) void dual_gemm_o(
    const f16* __restrict__ Ah, const f16* __restrict__ Al,
    const f16* __restrict__ Wph, const f16* __restrict__ Wpl,
    const f16* __restrict__ Wmh, const f16* __restrict__ Wml,
    const float* __restrict__ bias, const float* __restrict__ cost,
    const float* __restrict__ xres, float* __restrict__ outf) {
  __shared__ __align__(16) f16 smem[65536];
  dual_body<1, 2>(Ah, Al, Wph, Wpl, Wmh, Wml, bias, cost, Ah, Al, xres,
                  nullptr, nullptr, outf, smem, blockIdx.x << 8,
                  blockIdx.y << 7);
}

// ------------------------------------------------------- V transpose -------
__global__ __launch_bounds__(256) void transpose_v(
    const f16* __restrict__ Vh, const f16* __restrict__ Vl,
    f16* __restrict__ VTh, f16* __restrict__ VTl) {
  const int iz = blockIdx.z, b = iz & 3;
  const f16* src = (iz >> 2) ? Vl : Vh;
  f16* dst = (iz >> 2) ? VTl : VTh;
  const int d0 = blockIdx.x << 6, s0 = blockIdx.y << 6;
  __shared__ f16 tl[64][65];
  const int c = threadIdx.x & 63, r4 = threadIdx.x >> 6;
  const f16* vb = src + (size_t)b * S_ * D_;
#pragma unroll
  for (int i = 0; i < 16; ++i) {
    const int sr = (r4 << 4) + i;
    tl[sr][c] = vb[(size_t)(s0 + sr) * D_ + d0 + c];
  }
  __syncthreads();
  f16* db = dst + (size_t)b * D_ * S_;
#pragma unroll
  for (int i = 0; i < 16; ++i) {
    const int dr = (r4 << 4) + i;
    db[(size_t)(d0 + dr) * S_ + s0 + c] = tl[c][dr];
  }
}

// ------------------------------------------------- scores = q k^T / 32 -----
__global__ __launch_bounds__(256, 2) void scores_gemm(
    const f16* __restrict__ Qh, const f16* __restrict__ Ql,
    const f16* __restrict__ Kh, const f16* __restrict__ Kl,
    float* __restrict__ SC) {
  const int rt = blockIdx.x, ct = blockIdx.y, b = blockIdx.z;
  if (ct > rt) return;
  __shared__ __align__(16) f16 lQh[4096], lQl[4096], lKh[4096], lKl[4096];
  const int tid = threadIdx.x, wid = tid >> 6, lane = tid & 63;
  const int row0 = rt << 7, col0 = ct << 7;
  const int wr = (wid >> 1) << 6, wc = (wid & 1) << 6;
  const int arow = lane & 15, cb = lane >> 4;
  const f32x4 zero = {0.f, 0.f, 0.f, 0.f};
  f32x4 acc[4][4];
#pragma unroll
  for (int m = 0; m < 4; ++m)
#pragma unroll
    for (int n = 0; n < 4; ++n) acc[m][n] = zero;
  const f16* Qhb = Qh + ((size_t)b * S_ + row0) * D_;
  const f16* Qlb = Ql + ((size_t)b * S_ + row0) * D_;
  const f16* Khb = Kh + ((size_t)b * S_ + col0) * D_;
  const f16* Klb = Kl + ((size_t)b * S_ + col0) * D_;
  for (int k = 0; k < D_; k += 32) {
    stage_tile(Qhb + k, D_, lQh, wid, lane);
    stage_tile(Qlb + k, D_, lQl, wid, lane);
    stage_tile(Khb + k, D_, lKh, wid, lane);
    stage_tile(Klb + k, D_, lKl, wid, lane);
    __syncthreads();
    f16x8 bh[4], bl[4];
#pragma unroll
    for (int n = 0; n < 4; ++n) {
      const int bo = lds_off(wc + n * 16 + arow, cb);
      bh[n] = *(const f16x8*)&lKh[bo];
      bl[n] = *(const f16x8*)&lKl[bo];
    }
#pragma unroll
    for (int m = 0; m < 4; ++m) {
      const int ao = lds_off(wr + m * 16 + arow, cb);
      f16x8 ah = *(const f16x8*)&lQh[ao];
      f16x8 al = *(const f16x8*)&lQl[ao];
#pragma unroll
      for (int n = 0; n < 4; ++n) {
        acc[m][n] = MFMA16(ah, bh[n], acc[m][n]);
        acc[m][n] = MFMA16(ah, bl[n], acc[m][n]);
        acc[m][n] = MFMA16(al, bh[n], acc[m][n]);
      }
    }
    __syncthreads();
  }
  float* scb = SC + (size_t)b * S_ * S_;
#pragma unroll
  for (int m = 0; m < 4; ++m) {
    const int rb = row0 + wr + m * 16 + ((lane >> 4) << 2);
#pragma unroll
    for (int n = 0; n < 4; ++n) {
      const int col = col0 + wc + n * 16 + (lane & 15);
#pragma unroll
      for (int j = 0; j < 4; ++j)
        scb[(size_t)(rb + j) * S_ + col] = acc[m][n][j] * (1.f / 33554432.f);
    }
  }
}

// --------------------------- softmax (causal) + in-place hi/lo f16 pack ----
__global__ __launch_bounds__(256) void softmax_rows(float* __restrict__ SC) {
  const int r = blockIdx.x;
  const int s = r & 2047;
  float* rowf = SC + (size_t)r * S_;
  const int t = threadIdx.x, c0 = t << 3;
  float f[8];
  float4 u0 = *(const float4*)(rowf + c0);
  float4 u1 = *(const float4*)(rowf + c0 + 4);
  f[0] = u0.x; f[1] = u0.y; f[2] = u0.z; f[3] = u0.w;
  f[4] = u1.x; f[5] = u1.y; f[6] = u1.z; f[7] = u1.w;
  float mx = -3.0e38f;
#pragma unroll
  for (int j = 0; j < 8; ++j)
    if (c0 + j <= s) mx = fmaxf(mx, f[j]);
  for (int o = 32; o; o >>= 1) mx = fmaxf(mx, __shfl_xor(mx, o, 64));
  __shared__ float red[8];
  const int wid = t >> 6;
  if ((t & 63) == 0) red[wid] = mx;
  __syncthreads();
  mx = fmaxf(fmaxf(red[0], red[1]), fmaxf(red[2], red[3]));
  float e[8];
  float sum = 0.f;
#pragma unroll
  for (int j = 0; j < 8; ++j) {
    e[j] = (c0 + j <= s) ? expf(f[j] - mx) : 0.f;
    sum += e[j];
  }
  for (int o = 32; o; o >>= 1) sum += __shfl_xor(sum, o, 64);
  if ((t & 63) == 0) red[4 + wid] = sum;
  __syncthreads();
  sum = red[4] + red[5] + red[6] + red[7];
  f16* rowh = (f16*)rowf;
  __align__(16) f16 ph[8], pl[8];
#pragma unroll
  for (int j = 0; j < 8; ++j) {
    float p = (e[j] / sum) * 2048.f;
    ph[j] = (f16)p;
    pl[j] = (f16)(p - (float)ph[j]);
  }
  *(uint4*)(rowh + c0) = *(uint4*)ph;
  *(uint4*)(rowh + 2048 + c0) = *(uint4*)pl;
}

// --------------------------------------------------------- attn = P V ------
__global__ __launch_bounds__(256, 2) void pv_gemm(
    const f16* __restrict__ P, const f16* __restrict__ VTh,
    const f16* __restrict__ VTl, f16* __restrict__ Ath, f16* __restrict__ Atl) {
  const int rt = blockIdx.x, ct = blockIdx.y, b = blockIdx.z;
  __shared__ __align__(16) f16 lPh[4096], lPl[4096], lVh[4096], lVl[4096];
  const int tid = threadIdx.x, wid = tid >> 6, lane = tid & 63;
  const int row0 = rt << 7, col0 = ct << 7;
  const int wr = (wid >> 1) << 6, wc = (wid & 1) << 6;
  const int arow = lane & 15, cb = lane >> 4;
  const f32x4 zero = {0.f, 0.f, 0.f, 0.f};
  f32x4 acc[4][4];
#pragma unroll
  for (int m = 0; m < 4; ++m)
#pragma unroll
    for (int n = 0; n < 4; ++n) acc[m][n] = zero;
  const f16* Pb = P + ((size_t)b * S_ + row0) * 4096;
  const f16* Vhb = VTh + (size_t)b * D_ * S_ + (size_t)col0 * S_;
  const f16* Vlb = VTl + (size_t)b * D_ * S_ + (size_t)col0 * S_;
  const int kend = (rt + 1) << 7;
  for (int k = 0; k < kend; k += 32) {
    stage_tile(Pb + k, 4096, lPh, wid, lane);
    stage_tile(Pb + 2048 + k, 4096, lPl, wid, lane);
    stage_tile(Vhb + k, S_, lVh, wid, lane);
    stage_tile(Vlb + k, S_, lVl, wid, lane);
    __syncthreads();
    f16x8 bh[4], bl[4];
#pragma unroll
    for (int n = 0; n < 4; ++n) {
      const int bo = lds_off(wc + n * 16 + arow, cb);
      bh[n] = *(const f16x8*)&lVh[bo];
      bl[n] = *(const f16x8*)&lVl[bo];
    }
#pragma unroll
    for (int m = 0; m < 4; ++m) {
      const int ao = lds_off(wr + m * 16 + arow, cb);
      f16x8 ah = *(const f16x8*)&lPh[ao];
      f16x8 al = *(const f16x8*)&lPl[ao];
#pragma unroll
      for (int n = 0; n < 4; ++n) {
        acc[m][n] = MFMA16(ah, bh[n], acc[m][n]);
        acc[m][n] = MFMA16(ah, bl[n], acc[m][n]);
        acc[m][n] = MFMA16(al, bh[n], acc[m][n]);
      }
    }
    __syncthreads();
  }
  // acc = 2048*1024 * attn  -> attn = acc * 2^-21
#pragma unroll
  for (int m = 0; m < 4; ++m) {
    const int rb = row0 + wr + m * 16 + ((lane >> 4) << 2);
#pragma unroll
    for (int n = 0; n < 4; ++n) {
      const int col = col0 + wc + n * 16 + (lane & 15);
#pragma unroll
      for (int j = 0; j < 4; ++j) {
        const float at = acc[m][n][j] * (1.f / 2097152.f);
        const size_t off = ((size_t)b * S_ + rb + j) * D_ + col;
        f16 h, l; split1024(at, h, l);
        Ath[off] = h; Atl[off] = l;
      }
    }
  }
}

// ---------------------------------------------------------------- host -----
extern "C" void kernel_launch(void* const* d_in, const int* in_sizes, int n_in,
                              void* d_out, int out_size, void* d_ws, size_t ws_size,
                              hipStream_t stream) {
  (void)in_sizes; (void)n_in; (void)out_size; (void)ws_size;
  const float* x      = (const float*)d_in[0];
  const float* ln_g   = (const float*)d_in[1];
  const float* ln_b   = (const float*)d_in[2];
  const float* q_mu_w = (const float*)d_in[3];
  const float* q_mu_b = (const float*)d_in[4];
  const float* q_pro  = (const float*)d_in[5];
  const float* q_gate = (const float*)d_in[6];
  const float* k_mu_w = (const float*)d_in[7];
  const float* k_mu_b = (const float*)d_in[8];
  const float* k_pro  = (const float*)d_in[9];
  const float* k_gate = (const float*)d_in[10];
  const float* v_mu_w = (const float*)d_in[11];
  const float* v_mu_b = (const float*)d_in[12];
  const float* v_pro  = (const float*)d_in[13];
  const float* v_gate = (const float*)d_in[14];
  const float* o_mu_w = (const float*)d_in[15];
  const float* o_mu_b = (const float*)d_in[16];
  const float* o_pro  = (const float*)d_in[17];
  const float* o_gate = (const float*)d_in[18];

  char* w = (char*)d_ws;
  f16* WB = (f16*)w;                      // 8 x (hi 1M + lo 1M halfs) = 32MB
  const size_t WS = 2097152;
  f16* Lh  = (f16*)(w + 33554432);
  f16* Ll  = (f16*)(w + 50331648);
  f16* Qh  = (f16*)(w + 67108864);
  f16* Ql  = (f16*)(w + 83886080);
  f16* Kh  = (f16*)(w + 100663296);
  f16* Kl  = (f16*)(w + 117440512);
  f16* VTh = (f16*)(w + 134217728);
  f16* VTl = (f16*)(w + 150994944);
  float* SC = (float*)(w + 167772160);    // 64MB scores (later P hi/lo)
  float* COST = (float*)(w + 234881024);
  f16* Vh = (f16*)SC;                     // temp V before transpose
  f16* Vl = (f16*)(w + 184549376);
  f16* Ath = Qh;  f16* Atl = Ql;          // attn reuses Q space

  convert_w<<<dim3(1024, 8), 256, 0, stream>>>(
      q_pro, q_mu_w, k_pro, k_mu_w, v_pro, v_mu_w, o_pro, o_mu_w, WB);
  cost_k<<<4, 256, 0, stream>>>(q_gate, k_gate, v_gate, o_gate, COST);
  layernorm_k<<<8192, 256, 0, stream>>>(x, ln_g, ln_b, Lh, Ll);

  // fused Q/K/V duals: one dispatch, 768 blocks
  dual_gemm_qkv<<<dim3(32, 24), 512, 0, stream>>>(
      Lh, Ll, WB, q_mu_b, k_mu_b, v_mu_b, COST,
      Qh, Ql, Kh, Kl, Vh, Vl);

  transpose_v<<<dim3(16, 32, 8), 256, 0, stream>>>(Vh, Vl, VTh, VTl);
  scores_gemm<<<dim3(16, 16, 4), 256, 0, stream>>>(Qh, Ql, Kh, Kl, SC);
  softmax_rows<<<8192, 256, 0, stream>>>(SC);
  pv_gemm<<<dim3(16, 8, 4), 256, 0, stream>>>((const f16*)SC, VTh, VTl, Ath, Atl);

  dual_gemm_o<<<dim3(32, 8), 512, 0, stream>>>(
      Ath, Atl, WB + 6 * WS, WB + 6 * WS + 1048576, WB + 7 * WS, WB + 7 * WS + 1048576,
      o_mu_b, COST + 3072, x, (float*)d_out);
}

// Round 15
// 660.737 us; speedup vs baseline: 1.1275x; 1.0088x over previous
//
#include <hip/hip_runtime.h>
#include <hip/hip_bf16.h>
#include <cmath>
#include <cstdint>

typedef _Float16 f16;
typedef _Float16 f16x8 __attribute__((ext_vector_type(8)));
typedef float f32x4 __attribute__((ext_vector_type(4)));

#define D_ 1024
#define S_ 2048

// Split-fp16 fp32 emulation: tensor T stored as (hi, lo) f16 pair of T*1024;
// GEMM = 3 MFMA passes (hh, hl, lh).  3-pass REQUIRED wherever the result
// feeds (transitively) the rl>0 branch boundary; final O mu-GEMM -> 2-pass.
//
// Config = r14 best (666 us): fused QKV duals (grid 32x24) + v4 dual body +
// 4-wave attention.  This round: (1) merged preamble (convert_w+cost+LN in
// one dispatch), (2) causal-aware softmax (skip loads/stores past kend(row)).

__device__ __forceinline__ void gload_lds16(const void* g, void* l) {
  __builtin_amdgcn_global_load_lds(
      (const __attribute__((address_space(1))) void*)(unsigned long long)(uintptr_t)g,
      (__attribute__((address_space(3))) void*)(unsigned int)(uintptr_t)l,
      16, 0, 0);
}

__device__ __forceinline__ int lds_off(int row, int cb) {
  return (row << 5) + ((cb ^ ((row >> 1) & 3)) << 3);
}

__device__ __forceinline__ void split1024(float v, f16& h, f16& l) {
  float s = v * 1024.f;  // exact
  h = (f16)s;
  l = (f16)(s - (float)h);
}

#define MFMA16(a, b, c) __builtin_amdgcn_mfma_f32_16x16x32_f16((a), (b), (c), 0, 0, 0)

// 4-wave stage helper for the attention kernels.
__device__ __forceinline__ void stage_tile(const f16* __restrict__ src, int ld,
                                           f16* lds, int wid, int lane) {
  const int r = (wid << 5) + (lane >> 2);
  const int c = (lane & 3) ^ ((r >> 1) & 3);
  const f16* g0 = src + (size_t)r * ld + (c << 3);
  gload_lds16(g0, lds + (wid << 10));
  gload_lds16(g0 + (size_t)(ld << 4), lds + (wid << 10) + 512);
}

// ------------------- merged preamble: convert_w + cost + layernorm ---------
// blocks [0,8192): weight convert (by=b>>10, 1024 blocks per matrix)
// blocks [8192,8196): cost vectors
// blocks [8196,16388): layernorm rows
__global__ __launch_bounds__(256) void preamble_k(
    const float* __restrict__ s0, const float* __restrict__ s1,
    const float* __restrict__ s2, const float* __restrict__ s3,
    const float* __restrict__ s4, const float* __restrict__ s5,
    const float* __restrict__ s6, const float* __restrict__ s7,
    f16* __restrict__ dst,
    const float* __restrict__ g0, const float* __restrict__ g1,
    const float* __restrict__ g2, const float* __restrict__ g3,
    float* __restrict__ cost,
    const float* __restrict__ x, const float* __restrict__ lng,
    const float* __restrict__ lnb, f16* __restrict__ Lh,
    f16* __restrict__ Ll) {
  const int b = blockIdx.x, t = threadIdx.x;
  __shared__ float red[8];
  if (b < 8192) {
    const float* srcs[8] = {s0, s1, s2, s3, s4, s5, s6, s7};
    const int by = b >> 10;
    const float* sp = srcs[by];
    f16* hi = dst + (size_t)by * 2097152;
    f16* lo = hi + 1048576;
    const int i = (((b & 1023) << 8) + t) << 2;
    float4 f = *(const float4*)(sp + i);
    __align__(8) f16 h4[4], l4[4];
    split1024(f.x, h4[0], l4[0]); split1024(f.y, h4[1], l4[1]);
    split1024(f.z, h4[2], l4[2]); split1024(f.w, h4[3], l4[3]);
    *(uint2*)(hi + i) = *(uint2*)h4;
    *(uint2*)(lo + i) = *(uint2*)l4;
  } else if (b < 8196) {
    const int bx = b - 8192;
    const float* gp = bx == 0 ? g0 : bx == 1 ? g1 : bx == 2 ? g2 : g3;
    float4 v = *(const float4*)(gp + (t << 2));
    float mx = fmaxf(fmaxf(fabsf(v.x), fabsf(v.y)), fmaxf(fabsf(v.z), fabsf(v.w)));
    for (int o = 32; o; o >>= 1) mx = fmaxf(mx, __shfl_xor(mx, o, 64));
    if ((t & 63) == 0) red[t >> 6] = mx;
    __syncthreads();
    mx = fmaxf(fmaxf(red[0], red[1]), fmaxf(red[2], red[3]));
    const float den = mx + 1e-9f;
    float4 o = {v.x / den, v.y / den, v.z / den, v.w / den};
    *(float4*)(cost + (bx << 10) + (t << 2)) = o;
  } else {
    const int row = b - 8196;
    const float* xr = x + (size_t)row * D_;
    float4 v = *(const float4*)(xr + (t << 2));
    float s = v.x + v.y + v.z + v.w;
    float q = v.x * v.x + v.y * v.y + v.z * v.z + v.w * v.w;
    for (int o = 32; o; o >>= 1) { s += __shfl_xor(s, o, 64); q += __shfl_xor(q, o, 64); }
    const int wid = t >> 6;
    if ((t & 63) == 0) { red[wid] = s; red[4 + wid] = q; }
    __syncthreads();
    s = red[0] + red[1] + red[2] + red[3];
    q = red[4] + red[5] + red[6] + red[7];
    const float mean = s * (1.f / D_);
    const float var = q * (1.f / D_) - mean * mean;
    const float inv = 1.f / sqrtf(var + 1e-5f);
    float4 gv = *(const float4*)(lng + (t << 2));
    float4 bv = *(const float4*)(lnb + (t << 2));
    __align__(8) f16 h4[4], l4[4];
    split1024((v.x - mean) * inv * gv.x + bv.x, h4[0], l4[0]);
    split1024((v.y - mean) * inv * gv.y + bv.y, h4[1], l4[1]);
    split1024((v.z - mean) * inv * gv.z + bv.z, h4[2], l4[2]);
    split1024((v.w - mean) * inv * gv.w + bv.w, h4[3], l4[3]);
    const size_t off = (size_t)row * D_ + (t << 2);
    *(uint2*)(Lh + off) = *(uint2*)h4;
    *(uint2*)(Ll + off) = *(uint2*)l4;
  }
}

// --------- dual GEMM + SPL + branch, reg-pipelined phases (v4) -------------
#define MFMA_PHASE(N, BPH, BPL, BMH, BML)                                  \
  __builtin_amdgcn_sched_barrier(0);                                       \
  __builtin_amdgcn_s_setprio(1);                                           \
  _Pragma("unroll") for (int m = 0; m < 4; ++m)                            \
      accP[m][N] = MFMA16(ah[m], (BPH), accP[m][N]);                       \
  _Pragma("unroll") for (int m = 0; m < 4; ++m)                            \
      accP[m][N] = MFMA16(ah[m], (BPL), accP[m][N]);                       \
  _Pragma("unroll") for (int m = 0; m < 4; ++m)                            \
      accP[m][N] = MFMA16(al[m], (BPH), accP[m][N]);                       \
  _Pragma("unroll") for (int m = 0; m < 4; ++m)                            \
      accM[m][N] = MFMA16(ah[m], (BMH), accM[m][N]);                       \
  _Pragma("unroll") for (int m = 0; m < 4; ++m)                            \
      accM[m][N] = MFMA16(ah[m], (BML), accM[m][N]);                       \
  if (MUP == 3) {                                                          \
    _Pragma("unroll") for (int m = 0; m < 4; ++m)                          \
        accM[m][N] = MFMA16(al[m], (BMH), accM[m][N]);                     \
  }                                                                        \
  __builtin_amdgcn_s_setprio(0);

template <int EPI, int MUP>
__device__ __forceinline__ void dual_body(
    const f16* __restrict__ Ah, const f16* __restrict__ Al,
    const f16* __restrict__ Wph, const f16* __restrict__ Wpl,
    const f16* __restrict__ Wmh, const f16* __restrict__ Wml,
    const float* __restrict__ bias, const float* __restrict__ cost,
    const f16* __restrict__ passh, const f16* __restrict__ passl,
    const float* __restrict__ xres, f16* __restrict__ outh,
    f16* __restrict__ outl, float* __restrict__ outf,
    f16* smem, int row0, int col0) {
  const int tid = threadIdx.x, wid = tid >> 6, lane = tid & 63;
  const int wr = (wid >> 1) << 6, wc = (wid & 1) << 6;
  const int arow = lane & 15, cbk = lane >> 4;

  const int sr = tid >> 2;
  const int sc = ((tid & 3) ^ ((sr >> 1) & 3)) << 3;
  const int wbase = wid << 9;

  const f16* pA0 = Ah + (size_t)(row0 + sr) * D_ + sc;
  const f16* pA1 = Ah + (size_t)(row0 + 128 + sr) * D_ + sc;
  const f16* pL0 = Al + (size_t)(row0 + sr) * D_ + sc;
  const f16* pL1 = Al + (size_t)(row0 + 128 + sr) * D_ + sc;
  const f16* pPh = Wph + (size_t)(col0 + sr) * D_ + sc;
  const f16* pPl = Wpl + (size_t)(col0 + sr) * D_ + sc;
  const f16* pMh = Wmh + (size_t)(col0 + sr) * D_ + sc;
  const f16* pMl = Wml + (size_t)(col0 + sr) * D_ + sc;

  const f32x4 zero = {0.f, 0.f, 0.f, 0.f};
  f32x4 accP[4][4], accM[4][4];
#pragma unroll
  for (int m = 0; m < 4; ++m)
#pragma unroll
    for (int n = 0; n < 4; ++n) { accP[m][n] = zero; accM[m][n] = zero; }

  int aoff[4], boff[4];
#pragma unroll
  for (int m = 0; m < 4; ++m) aoff[m] = lds_off(wr + m * 16 + arow, cbk);
#pragma unroll
  for (int n = 0; n < 4; ++n) boff[n] = lds_off(wc + n * 16 + arow, cbk);

  {
    f16* b = smem;
    gload_lds16(pA0, b + wbase);          gload_lds16(pA1, b + 4096 + wbase);
    gload_lds16(pL0, b + 8192 + wbase);   gload_lds16(pL1, b + 12288 + wbase);
    gload_lds16(pPh, b + 16384 + wbase);  gload_lds16(pPl, b + 20480 + wbase);
    gload_lds16(pMh, b + 24576 + wbase);  gload_lds16(pMl, b + 28672 + wbase);
  }
  asm volatile("s_waitcnt vmcnt(0)" ::: "memory");
  __builtin_amdgcn_s_barrier();
  __builtin_amdgcn_sched_barrier(0);

  int cur = 0;
  for (int t = 0; t < 32; ++t) {
    const f16* bb = smem + (cur << 15);
    f16* nb = smem + ((cur ^ 1) << 15);
    const int kn = (t < 31) ? ((t + 1) << 5) : 0;

    f16x8 ah[4], al[4];
#pragma unroll
    for (int m = 0; m < 4; ++m) {
      ah[m] = *(const f16x8*)&bb[aoff[m]];
      al[m] = *(const f16x8*)&bb[8192 + aoff[m]];
    }
    f16x8 xph = *(const f16x8*)&bb[16384 + boff[0]];
    f16x8 xpl = *(const f16x8*)&bb[20480 + boff[0]];
    f16x8 xmh = *(const f16x8*)&bb[24576 + boff[0]];
    f16x8 xml = *(const f16x8*)&bb[28672 + boff[0]];
    f16x8 yph = *(const f16x8*)&bb[16384 + boff[1]];
    f16x8 ypl = *(const f16x8*)&bb[20480 + boff[1]];
    f16x8 ymh = *(const f16x8*)&bb[24576 + boff[1]];
    f16x8 yml = *(const f16x8*)&bb[28672 + boff[1]];
    gload_lds16(pA0 + kn, nb + wbase);
    gload_lds16(pA1 + kn, nb + 4096 + wbase);
    MFMA_PHASE(0, xph, xpl, xmh, xml)

    xph = *(const f16x8*)&bb[16384 + boff[2]];
    xpl = *(const f16x8*)&bb[20480 + boff[2]];
    xmh = *(const f16x8*)&bb[24576 + boff[2]];
    xml = *(const f16x8*)&bb[28672 + boff[2]];
    gload_lds16(pL0 + kn, nb + 8192 + wbase);
    gload_lds16(pL1 + kn, nb + 12288 + wbase);
    MFMA_PHASE(1, yph, ypl, ymh, yml)

    yph = *(const f16x8*)&bb[16384 + boff[3]];
    ypl = *(const f16x8*)&bb[20480 + boff[3]];
    ymh = *(const f16x8*)&bb[24576 + boff[3]];
    yml = *(const f16x8*)&bb[28672 + boff[3]];
    gload_lds16(pPh + kn, nb + 16384 + wbase);
    gload_lds16(pPl + kn, nb + 20480 + wbase);
    MFMA_PHASE(2, xph, xpl, xmh, xml)

    gload_lds16(pMh + kn, nb + 24576 + wbase);
    gload_lds16(pMl + kn, nb + 28672 + wbase);
    MFMA_PHASE(3, yph, ypl, ymh, yml)

    asm volatile("s_waitcnt vmcnt(0)" ::: "memory");
    __builtin_amdgcn_s_barrier();
    __builtin_amdgcn_sched_barrier(0);
    cur ^= 1;
  }

  // acc = 2^20 * true.  match = acc*2^-25 (incl /32); pre = acc*2^-20.
#pragma unroll
  for (int m = 0; m < 4; ++m) {
    const int rb = row0 + wr + m * 16 + ((lane >> 4) << 2);
#pragma unroll
    for (int n = 0; n < 4; ++n) {
      const int col = col0 + wc + n * 16 + (lane & 15);
      const float cb2 = cost[col], bbv = bias[col];
#pragma unroll
      for (int j = 0; j < 4; ++j) {
        const size_t off = (size_t)(rb + j) * D_ + col;
        const float match = accP[m][n][j] * (1.f / 33554432.f);
        const float pre = accM[m][n][j] * (1.f / 1048576.f) + bbv;
        const float comp = pre / (1.f + expf(-pre));
        const float rl = match - cb2;
        float ov;
        if (rl > 0.f) ov = comp * rl;
        else ov = ((float)passh[off] + (float)passl[off]) * (1.f / 1024.f);
        if (EPI == 0) {
          f16 h, l; split1024(ov, h, l);
          outh[off] = h; outl[off] = l;
        } else {
          outf[off] = xres[off] + ov;
        }
      }
    }
  }
}

// Fused Q/K/V duals: one dispatch, grid (32, 24); branch = blockIdx.y>>3.
__global__ __launch_bounds__(512, 1) void dual_gemm_qkv(
    const f16* __restrict__ Ah, const f16* __restrict__ Al,
    const f16* __restrict__ WB,
    const float* __restrict__ qb, const float* __restrict__ kb,
    const float* __restrict__ vb, const float* __restrict__ COST,
    f16* __restrict__ Qh, f16* __restrict__ Ql,
    f16* __restrict__ Kh, f16* __restrict__ Kl,
    f16* __restrict__ Vh, f16* __restrict__ Vl) {
  __shared__ __align__(16) f16 smem[65536];
  const int br = blockIdx.y >> 3;
  const int row0 = blockIdx.x << 8;
  const int col0 = (blockIdx.y & 7) << 7;
  const f16* Wph = WB + (size_t)br * 4194304;
  const f16* Wpl = Wph + 1048576;
  const f16* Wmh = Wph + 2097152;
  const f16* Wml = Wph + 3145728;
  const float* bias = br == 0 ? qb : br == 1 ? kb : vb;
  const float* cost = COST + (br << 10);
  f16* outh = br == 0 ? Qh : br == 1 ? Kh : Vh;
  f16* outl = br == 0 ? Ql : br == 1 ? Kl : Vl;
  dual_body<0, 3>(Ah, Al, Wph, Wpl, Wmh, Wml, bias, cost, Ah, Al, nullptr,
                  outh, outl, nullptr, smem, row0, col0);
}

// O-branch dual (EPI=1, 2-pass mu).
__global__ __launch_bounds__(512, 1) void dual_gemm_o(
    const f16* __restrict__ Ah, const f16* __restrict__ Al,
    const f16* __restrict__ Wph, const f16* __restrict__ Wpl,
    const f16* __restrict__ Wmh, const f16* __restrict__ Wml,
    const float* __restrict__ bias, const float* __restrict__ cost,
    const float* __restrict__ xres, float* __restrict__ outf) {
  __shared__ __align__(16) f16 smem[65536];
  dual_body<1, 2>(Ah, Al, Wph, Wpl, Wmh, Wml, bias, cost, Ah, Al, xres,
                  nullptr, nullptr, outf, smem, blockIdx.x << 8,
                  blockIdx.y << 7);
}

// ------------------------------------------------------- V transpose -------
__global__ __launch_bounds__(256) void transpose_v(
    const f16* __restrict__ Vh, const f16* __restrict__ Vl,
    f16* __restrict__ VTh, f16* __restrict__ VTl) {
  const int iz = blockIdx.z, b = iz & 3;
  const f16* src = (iz >> 2) ? Vl : Vh;
  f16* dst = (iz >> 2) ? VTl : VTh;
  const int d0 = blockIdx.x << 6, s0 = blockIdx.y << 6;
  __shared__ f16 tl[64][65];
  const int c = threadIdx.x & 63, r4 = threadIdx.x >> 6;
  const f16* vb = src + (size_t)b * S_ * D_;
#pragma unroll
  for (int i = 0; i < 16; ++i) {
    const int sr = (r4 << 4) + i;
    tl[sr][c] = vb[(size_t)(s0 + sr) * D_ + d0 + c];
  }
  __syncthreads();
  f16* db = dst + (size_t)b * D_ * S_;
#pragma unroll
  for (int i = 0; i < 16; ++i) {
    const int dr = (r4 << 4) + i;
    db[(size_t)(d0 + dr) * S_ + s0 + c] = tl[c][dr];
  }
}

// ------------------------------------------------- scores = q k^T / 32 -----
__global__ __launch_bounds__(256, 2) void scores_gemm(
    const f16* __restrict__ Qh, const f16* __restrict__ Ql,
    const f16* __restrict__ Kh, const f16* __restrict__ Kl,
    float* __restrict__ SC) {
  const int rt = blockIdx.x, ct = blockIdx.y, b = blockIdx.z;
  if (ct > rt) return;
  __shared__ __align__(16) f16 lQh[4096], lQl[4096], lKh[4096], lKl[4096];
  const int tid = threadIdx.x, wid = tid >> 6, lane = tid & 63;
  const int row0 = rt << 7, col0 = ct << 7;
  const int wr = (wid >> 1) << 6, wc = (wid & 1) << 6;
  const int arow = lane & 15, cb = lane >> 4;
  const f32x4 zero = {0.f, 0.f, 0.f, 0.f};
  f32x4 acc[4][4];
#pragma unroll
  for (int m = 0; m < 4; ++m)
#pragma unroll
    for (int n = 0; n < 4; ++n) acc[m][n] = zero;
  const f16* Qhb = Qh + ((size_t)b * S_ + row0) * D_;
  const f16* Qlb = Ql + ((size_t)b * S_ + row0) * D_;
  const f16* Khb = Kh + ((size_t)b * S_ + col0) * D_;
  const f16* Klb = Kl + ((size_t)b * S_ + col0) * D_;
  for (int k = 0; k < D_; k += 32) {
    stage_tile(Qhb + k, D_, lQh, wid, lane);
    stage_tile(Qlb + k, D_, lQl, wid, lane);
    stage_tile(Khb + k, D_, lKh, wid, lane);
    stage_tile(Klb + k, D_, lKl, wid, lane);
    __syncthreads();
    f16x8 bh[4], bl[4];
#pragma unroll
    for (int n = 0; n < 4; ++n) {
      const int bo = lds_off(wc + n * 16 + arow, cb);
      bh[n] = *(const f16x8*)&lKh[bo];
      bl[n] = *(const f16x8*)&lKl[bo];
    }
#pragma unroll
    for (int m = 0; m < 4; ++m) {
      const int ao = lds_off(wr + m * 16 + arow, cb);
      f16x8 ah = *(const f16x8*)&lQh[ao];
      f16x8 al = *(const f16x8*)&lQl[ao];
#pragma unroll
      for (int n = 0; n < 4; ++n) {
        acc[m][n] = MFMA16(ah, bh[n], acc[m][n]);
        acc[m][n] = MFMA16(ah, bl[n], acc[m][n]);
        acc[m][n] = MFMA16(al, bh[n], acc[m][n]);
      }
    }
    __syncthreads();
  }
  float* scb = SC + (size_t)b * S_ * S_;
#pragma unroll
  for (int m = 0; m < 4; ++m) {
    const int rb = row0 + wr + m * 16 + ((lane >> 4) << 2);
#pragma unroll
    for (int n = 0; n < 4; ++n) {
      const int col = col0 + wc + n * 16 + (lane & 15);
#pragma unroll
      for (int j = 0; j < 4; ++j)
        scb[(size_t)(rb + j) * S_ + col] = acc[m][n][j] * (1.f / 33554432.f);
    }
  }
}

// ----------- softmax (causal, traffic-skipped) + in-place f16 pack ---------
__global__ __launch_bounds__(256) void softmax_rows(float* __restrict__ SC) {
  const int r = blockIdx.x;
  const int s = r & 2047;
  const int limit = ((s >> 7) + 1) << 7;  // kend for this row (mult of 128)
  float* rowf = SC + (size_t)r * S_;
  const int t = threadIdx.x, c0 = t << 3;
  const bool active = c0 < limit;  // c0 mult of 8, limit mult of 128
  float f[8] = {0, 0, 0, 0, 0, 0, 0, 0};
  if (active) {
    float4 u0 = *(const float4*)(rowf + c0);
    float4 u1 = *(const float4*)(rowf + c0 + 4);
    f[0] = u0.x; f[1] = u0.y; f[2] = u0.z; f[3] = u0.w;
    f[4] = u1.x; f[5] = u1.y; f[6] = u1.z; f[7] = u1.w;
  }
  float mx = -3.0e38f;
#pragma unroll
  for (int j = 0; j < 8; ++j)
    if (c0 + j <= s) mx = fmaxf(mx, f[j]);
  for (int o = 32; o; o >>= 1) mx = fmaxf(mx, __shfl_xor(mx, o, 64));
  __shared__ float red[8];
  const int wid = t >> 6;
  if ((t & 63) == 0) red[wid] = mx;
  __syncthreads();
  mx = fmaxf(fmaxf(red[0], red[1]), fmaxf(red[2], red[3]));
  float e[8];
  float sum = 0.f;
#pragma unroll
  for (int j = 0; j < 8; ++j) {
    e[j] = (c0 + j <= s) ? expf(f[j] - mx) : 0.f;
    sum += e[j];
  }
  for (int o = 32; o; o >>= 1) sum += __shfl_xor(sum, o, 64);
  if ((t & 63) == 0) red[4 + wid] = sum;
  __syncthreads();
  sum = red[4] + red[5] + red[6] + red[7];
  if (active) {
    f16* rowh = (f16*)rowf;
    __align__(16) f16 ph[8], pl[8];
#pragma unroll
    for (int j = 0; j < 8; ++j) {
      float p = (e[j] / sum) * 2048.f;
      ph[j] = (f16)p;
      pl[j] = (f16)(p - (float)ph[j]);
    }
    *(uint4*)(rowh + c0) = *(uint4*)ph;
    *(uint4*)(rowh + 2048 + c0) = *(uint4*)pl;
  }
}

// --------------------------------------------------------- attn = P V ------
__global__ __launch_bounds__(256, 2) void pv_gemm(
    const f16* __restrict__ P, const f16* __restrict__ VTh,
    const f16* __restrict__ VTl, f16* __restrict__ Ath, f16* __restrict__ Atl) {
  const int rt = blockIdx.x, ct = blockIdx.y, b = blockIdx.z;
  __shared__ __align__(16) f16 lPh[4096], lPl[4096], lVh[4096], lVl[4096];
  const int tid = threadIdx.x, wid = tid >> 6, lane = tid & 63;
  const int row0 = rt << 7, col0 = ct << 7;
  const int wr = (wid >> 1) << 6, wc = (wid & 1) << 6;
  const int arow = lane & 15, cb = lane >> 4;
  const f32x4 zero = {0.f, 0.f, 0.f, 0.f};
  f32x4 acc[4][4];
#pragma unroll
  for (int m = 0; m < 4; ++m)
#pragma unroll
    for (int n = 0; n < 4; ++n) acc[m][n] = zero;
  const f16* Pb = P + ((size_t)b * S_ + row0) * 4096;
  const f16* Vhb = VTh + (size_t)b * D_ * S_ + (size_t)col0 * S_;
  const f16* Vlb = VTl + (size_t)b * D_ * S_ + (size_t)col0 * S_;
  const int kend = (rt + 1) << 7;
  for (int k = 0; k < kend; k += 32) {
    stage_tile(Pb + k, 4096, lPh, wid, lane);
    stage_tile(Pb + 2048 + k, 4096, lPl, wid, lane);
    stage_tile(Vhb + k, S_, lVh, wid, lane);
    stage_tile(Vlb + k, S_, lVl, wid, lane);
    __syncthreads();
    f16x8 bh[4], bl[4];
#pragma unroll
    for (int n = 0; n < 4; ++n) {
      const int bo = lds_off(wc + n * 16 + arow, cb);
      bh[n] = *(const f16x8*)&lVh[bo];
      bl[n] = *(const f16x8*)&lVl[bo];
    }
#pragma unroll
    for (int m = 0; m < 4; ++m) {
      const int ao = lds_off(wr + m * 16 + arow, cb);
      f16x8 ah = *(const f16x8*)&lPh[ao];
      f16x8 al = *(const f16x8*)&lPl[ao];
#pragma unroll
      for (int n = 0; n < 4; ++n) {
        acc[m][n] = MFMA16(ah, bh[n], acc[m][n]);
        acc[m][n] = MFMA16(ah, bl[n], acc[m][n]);
        acc[m][n] = MFMA16(al, bh[n], acc[m][n]);
      }
    }
    __syncthreads();
  }
  // acc = 2048*1024 * attn  -> attn = acc * 2^-21
#pragma unroll
  for (int m = 0; m < 4; ++m) {
    const int rb = row0 + wr + m * 16 + ((lane >> 4) << 2);
#pragma unroll
    for (int n = 0; n < 4; ++n) {
      const int col = col0 + wc + n * 16 + (lane & 15);
#pragma unroll
      for (int j = 0; j < 4; ++j) {
        const float at = acc[m][n][j] * (1.f / 2097152.f);
        const size_t off = ((size_t)b * S_ + rb + j) * D_ + col;
        f16 h, l; split1024(at, h, l);
        Ath[off] = h; Atl[off] = l;
      }
    }
  }
}

// ---------------------------------------------------------------- host -----
extern "C" void kernel_launch(void* const* d_in, const int* in_sizes, int n_in,
                              void* d_out, int out_size, void* d_ws, size_t ws_size,
                              hipStream_t stream) {
  (void)in_sizes; (void)n_in; (void)out_size; (void)ws_size;
  const float* x      = (const float*)d_in[0];
  const float* ln_g   = (const float*)d_in[1];
  const float* ln_b   = (const float*)d_in[2];
  const float* q_mu_w = (const float*)d_in[3];
  const float* q_mu_b = (const float*)d_in[4];
  const float* q_pro  = (const float*)d_in[5];
  const float* q_gate = (const float*)d_in[6];
  const float* k_mu_w = (const float*)d_in[7];
  const float* k_mu_b = (const float*)d_in[8];
  const float* k_pro  = (const float*)d_in[9];
  const float* k_gate = (const float*)d_in[10];
  const float* v_mu_w = (const float*)d_in[11];
  const float* v_mu_b = (const float*)d_in[12];
  const float* v_pro  = (const float*)d_in[13];
  const float* v_gate = (const float*)d_in[14];
  const float* o_mu_w = (const float*)d_in[15];
  const float* o_mu_b = (const float*)d_in[16];
  const float* o_pro  = (const float*)d_in[17];
  const float* o_gate = (const float*)d_in[18];

  char* w = (char*)d_ws;
  f16* WB = (f16*)w;                      // 8 x (hi 1M + lo 1M halfs) = 32MB
  const size_t WS = 2097152;
  f16* Lh  = (f16*)(w + 33554432);
  f16* Ll  = (f16*)(w + 50331648);
  f16* Qh  = (f16*)(w + 67108864);
  f16* Ql  = (f16*)(w + 83886080);
  f16* Kh  = (f16*)(w + 100663296);
  f16* Kl  = (f16*)(w + 117440512);
  f16* VTh = (f16*)(w + 134217728);
  f16* VTl = (f16*)(w + 150994944);
  float* SC = (float*)(w + 167772160);    // 64MB scores (later P hi/lo)
  float* COST = (float*)(w + 234881024);
  f16* Vh = (f16*)SC;                     // temp V before transpose
  f16* Vl = (f16*)(w + 184549376);
  f16* Ath = Qh;  f16* Atl = Ql;          // attn reuses Q space

  preamble_k<<<16388, 256, 0, stream>>>(
      q_pro, q_mu_w, k_pro, k_mu_w, v_pro, v_mu_w, o_pro, o_mu_w, WB,
      q_gate, k_gate, v_gate, o_gate, COST, x, ln_g, ln_b, Lh, Ll);

  dual_gemm_qkv<<<dim3(32, 24), 512, 0, stream>>>(
      Lh, Ll, WB, q_mu_b, k_mu_b, v_mu_b, COST,
      Qh, Ql, Kh, Kl, Vh, Vl);

  transpose_v<<<dim3(16, 32, 8), 256, 0, stream>>>(Vh, Vl, VTh, VTl);
  scores_gemm<<<dim3(16, 16, 4), 256, 0, stream>>>(Qh, Ql, Kh, Kl, SC);
  softmax_rows<<<8192, 256, 0, stream>>>(SC);
  pv_gemm<<<dim3(16, 8, 4), 256, 0, stream>>>((const f16*)SC, VTh, VTl, Ath, Atl);

  dual_gemm_o<<<dim3(32, 8), 512, 0, stream>>>(
      Ath, Atl, WB + 6 * WS, WB + 6 * WS + 1048576, WB + 7 * WS, WB + 7 * WS + 1048576,
      o_mu_b, COST + 3072, x, (float*)d_out);
}